// Round 1
// baseline (6976.165 us; speedup 1.0000x reference)
//
#include <hip/hip_runtime.h>
#include <hip/hip_bf16.h>
#include <math.h>

// Problem constants
#define BB 4
#define SS 1024
#define DD 1024
#define EE 4
#define HID 2816
#define HC 704          // HID chunk (2816 = 4*704), multiple of 64
#define SIXD 6144

// ---------------------------------------------------------------------------
// Tiled fp32 GEMM: 64x64 tile, K-tile 16, 256 threads, 4x4 accum per thread.
// MODE 0: C = A(MxK) * B(KxN)        (NN)
// MODE 1: C = A^T where A stored KxM (TN)  -> C[m,n] = sum_k A[k*lda+m]*B[k*ldb+n]
// MODE 2: B stored NxK (NT)              -> C[m,n] = sum_k A[m*lda+k]*B[n*ldb+k]
// All of M,N multiples of 64; K multiple of 16. Batched via blockIdx.z.
// ---------------------------------------------------------------------------
template<int MODE, bool ACCUM>
__global__ __launch_bounds__(256) void gemm64(
    const float* __restrict__ A, const float* __restrict__ B, float* __restrict__ C,
    int M, int N, int K, int lda, int ldb, int ldc,
    long sA, long sB, long sC)
{
    __shared__ float As[16][65];
    __shared__ float Bs[16][65];
    const int tid = threadIdx.x;
    const int tx = tid & 15, ty = tid >> 4;
    const int m0 = blockIdx.y * 64, n0 = blockIdx.x * 64;
    A += (long)blockIdx.z * sA;
    B += (long)blockIdx.z * sB;
    C += (long)blockIdx.z * sC;

    float acc[4][4] = {};
    for (int k0 = 0; k0 < K; k0 += 16) {
        // ---- load A tile into As[k][m] ----
        if (MODE == 1) {           // A is K x M
            const int kk = tid >> 4;           // 0..15
            const int mq = (tid & 15) * 4;     // 0..60
            const float4 v = *(const float4*)(A + (long)(k0 + kk) * lda + m0 + mq);
            As[kk][mq+0]=v.x; As[kk][mq+1]=v.y; As[kk][mq+2]=v.z; As[kk][mq+3]=v.w;
        } else {                   // A is M x K
            const int m  = tid >> 2;           // 0..63
            const int kq = (tid & 3) * 4;      // 0,4,8,12
            const float4 v = *(const float4*)(A + (long)(m0 + m) * lda + k0 + kq);
            As[kq+0][m]=v.x; As[kq+1][m]=v.y; As[kq+2][m]=v.z; As[kq+3][m]=v.w;
        }
        // ---- load B tile into Bs[k][n] ----
        if (MODE == 2) {           // B is N x K
            const int n  = tid >> 2;
            const int kq = (tid & 3) * 4;
            const float4 v = *(const float4*)(B + (long)(n0 + n) * ldb + k0 + kq);
            Bs[kq+0][n]=v.x; Bs[kq+1][n]=v.y; Bs[kq+2][n]=v.z; Bs[kq+3][n]=v.w;
        } else {                   // B is K x N
            const int kk = tid >> 4;
            const int nq = (tid & 15) * 4;
            const float4 v = *(const float4*)(B + (long)(k0 + kk) * ldb + n0 + nq);
            Bs[kk][nq+0]=v.x; Bs[kk][nq+1]=v.y; Bs[kk][nq+2]=v.z; Bs[kk][nq+3]=v.w;
        }
        __syncthreads();
        #pragma unroll
        for (int kk = 0; kk < 16; ++kk) {
            float a[4], b[4];
            #pragma unroll
            for (int i = 0; i < 4; ++i) a[i] = As[kk][ty + 16*i];
            #pragma unroll
            for (int j = 0; j < 4; ++j) b[j] = Bs[kk][tx + 16*j];
            #pragma unroll
            for (int i = 0; i < 4; ++i)
                #pragma unroll
                for (int j = 0; j < 4; ++j)
                    acc[i][j] += a[i] * b[j];
        }
        __syncthreads();
    }
    #pragma unroll
    for (int i = 0; i < 4; ++i) {
        const int m = m0 + ty + 16*i;
        #pragma unroll
        for (int j = 0; j < 4; ++j) {
            const int n = n0 + tx + 16*j;
            const long idx = (long)m * ldc + n;
            if (ACCUM) C[idx] += acc[i][j]; else C[idx] = acc[i][j];
        }
    }
}

// ---------------------------------------------------------------------------
// adaLN: ada[b, n] = sum_k silu(adaln[b,k]) * ada_w[k,n] + ada_b[n]
// grid (SIXD/256, B), block 256
// ---------------------------------------------------------------------------
__global__ __launch_bounds__(256) void ada_kernel(
    const float* __restrict__ adaln, const float* __restrict__ aw,
    const float* __restrict__ ab, float* __restrict__ ada)
{
    __shared__ float s[DD];
    const int b = blockIdx.y;
    const int tid = threadIdx.x;
    for (int i = tid; i < DD; i += 256) {
        const float v = adaln[(long)b * DD + i];
        s[i] = v / (1.f + expf(-v));     // silu
    }
    __syncthreads();
    const int n = blockIdx.x * 256 + tid;
    float acc = 0.f;
    for (int k = 0; k < DD; ++k) acc += s[k] * aw[(long)k * SIXD + n];
    ada[(long)b * SIXD + n] = acc + ab[n];
}

// ---------------------------------------------------------------------------
// LayerNorm over D=1024 (one block per row), optional adaLN modulate.
// ---------------------------------------------------------------------------
template<bool MOD>
__global__ __launch_bounds__(256) void ln_kernel(
    const float* __restrict__ x, const float* __restrict__ w, const float* __restrict__ bias,
    const float* __restrict__ ada, int scale_off, int shift_off,
    float* __restrict__ out, float eps)
{
    const int row = blockIdx.x;
    const int b = row >> 10;          // row / S
    const int tid = threadIdx.x;
    const float* xr = x + (long)row * DD;
    float v[4]; float s = 0.f, q = 0.f;
    #pragma unroll
    for (int i = 0; i < 4; ++i) { v[i] = xr[tid + 256*i]; s += v[i]; q += v[i]*v[i]; }
    __shared__ float rs_[256], rq_[256];
    rs_[tid] = s; rq_[tid] = q; __syncthreads();
    for (int off = 128; off > 0; off >>= 1) {
        if (tid < off) { rs_[tid] += rs_[tid+off]; rq_[tid] += rq_[tid+off]; }
        __syncthreads();
    }
    const float mu  = rs_[0] * (1.f/DD);
    const float var = rq_[0] * (1.f/DD) - mu*mu;
    const float rstd = rsqrtf(var + eps);
    const float* ar = ada + (long)b * SIXD;
    float* orow = out + (long)row * DD;
    #pragma unroll
    for (int i = 0; i < 4; ++i) {
        const int d = tid + 256*i;
        float y = (v[i] - mu) * rstd * w[d] + bias[d];
        if (MOD) y = y * (1.f + ar[scale_off + d]) + ar[shift_off + d];
        orow[d] = y;
    }
}

// ---------------------------------------------------------------------------
// Row softmax over 1024 (stable), in place. one block per row
// ---------------------------------------------------------------------------
__global__ __launch_bounds__(256) void softmax1024(float* __restrict__ data)
{
    const long row = blockIdx.x;
    float* p = data + row * 1024;
    const int tid = threadIdx.x;
    float v[4]; float mx = -INFINITY;
    #pragma unroll
    for (int i = 0; i < 4; ++i) { v[i] = p[tid + 256*i]; mx = fmaxf(mx, v[i]); }
    __shared__ float red[256];
    red[tid] = mx; __syncthreads();
    for (int off = 128; off > 0; off >>= 1) {
        if (tid < off) red[tid] = fmaxf(red[tid], red[tid+off]);
        __syncthreads();
    }
    const float rowmax = red[0];
    __syncthreads();
    float s = 0.f;
    #pragma unroll
    for (int i = 0; i < 4; ++i) { v[i] = expf(v[i] - rowmax); s += v[i]; }
    red[tid] = s; __syncthreads();
    for (int off = 128; off > 0; off >>= 1) {
        if (tid < off) red[tid] += red[tid+off];
        __syncthreads();
    }
    const float inv = 1.f / red[0];
    #pragma unroll
    for (int i = 0; i < 4; ++i) p[tid + 256*i] = v[i] * inv;
}

// x2 = x + gate_msa[b,d] * proj ; gate_msa at ada offset 2048
__global__ __launch_bounds__(256) void resgate_kernel(
    const float* __restrict__ x, const float* __restrict__ proj,
    const float* __restrict__ ada, float* __restrict__ out)
{
    const long i = (long)blockIdx.x * 256 + threadIdx.x;
    const int d = (int)(i & 1023);
    const int b = (int)(i >> 20);     // / (S*D)
    out[i] = x[i] + ada[(long)b * SIXD + 2048 + d] * proj[i];
}

// router logits: one block per (b,s) row
__global__ __launch_bounds__(256) void router_logits_kernel(
    const float* __restrict__ h, const float* __restrict__ rw,
    const float* __restrict__ rb, float* __restrict__ logits)
{
    const long row = blockIdx.x;
    const int tid = threadIdx.x;
    float acc[4] = {0.f,0.f,0.f,0.f};
    for (int k = tid; k < DD; k += 256) {
        const float hv = h[row * DD + k];
        const float* r = rw + (long)k * EE;
        acc[0] += hv*r[0]; acc[1] += hv*r[1]; acc[2] += hv*r[2]; acc[3] += hv*r[3];
    }
    __shared__ float red[256];
    for (int e = 0; e < EE; ++e) {
        __syncthreads();
        red[tid] = acc[e]; __syncthreads();
        for (int off = 128; off > 0; off >>= 1) {
            if (tid < off) red[tid] += red[tid+off];
            __syncthreads();
        }
        if (tid == 0) logits[row * EE + e] = red[0] + rb[e];
    }
}

// L2 norm along sequence dim: one block per (b,e)
__global__ __launch_bounds__(256) void router_norm_kernel(
    const float* __restrict__ logits, float* __restrict__ nrm)
{
    const int b = blockIdx.x >> 2, e = blockIdx.x & 3;
    const int tid = threadIdx.x;
    float s = 0.f;
    for (int si = tid; si < SS; si += 256) {
        const float v = logits[((long)b * SS + si) * EE + e];
        s += v * v;
    }
    __shared__ float red[256];
    red[tid] = s; __syncthreads();
    for (int off = 128; off > 0; off >>= 1) {
        if (tid < off) red[tid] += red[tid+off];
        __syncthreads();
    }
    if (tid == 0) nrm[blockIdx.x] = sqrtf(red[0]);
}

// normalize, softmax over E=4, top-2 -> probs + combine weights. one thread/(b,s)
__global__ __launch_bounds__(256) void router_post_kernel(
    const float* __restrict__ logits, const float* __restrict__ nrm,
    float* __restrict__ probs, float* __restrict__ combine)
{
    const long row = (long)blockIdx.x * 256 + threadIdx.x;   // 0..4095
    const int b = (int)(row >> 10);
    float l[4], p[4];
    #pragma unroll
    for (int e = 0; e < 4; ++e)
        l[e] = logits[row*4 + e] / fmaxf(nrm[b*4 + e], 1e-12f);
    const float mx = fmaxf(fmaxf(l[0], l[1]), fmaxf(l[2], l[3]));
    float s = 0.f;
    #pragma unroll
    for (int e = 0; e < 4; ++e) { p[e] = expf(l[e] - mx); s += p[e]; }
    const float inv = 1.f / s;
    #pragma unroll
    for (int e = 0; e < 4; ++e) { p[e] *= inv; probs[row*4 + e] = p[e]; }
    // top-2 (stable by index, matches jax.lax.top_k)
    int i1 = 0;
    #pragma unroll
    for (int e = 1; e < 4; ++e) if (p[e] > p[i1]) i1 = e;
    int i2 = (i1 == 0) ? 1 : 0;
    #pragma unroll
    for (int e = 0; e < 4; ++e) if (e != i1 && p[e] > p[i2]) i2 = e;
    float c[4] = {0.f,0.f,0.f,0.f};
    c[i1] = p[i1]; c[i2] = p[i2];
    #pragma unroll
    for (int e = 0; e < 4; ++e) combine[row*4 + e] = c[e];
}

// aux = sum_{s,e} (1/E - mean_b probs)^2 ; single block
__global__ __launch_bounds__(256) void aux_kernel(
    const float* __restrict__ probs, float* __restrict__ aux)
{
    const int tid = threadIdx.x;
    float acc = 0.f;
    for (int i = tid; i < SS*EE; i += 256) {
        const float avg = 0.25f * (probs[i] + probs[SS*EE + i] +
                                   probs[2*SS*EE + i] + probs[3*SS*EE + i]);
        const float d = 0.25f - avg;
        acc += d * d;
    }
    __shared__ float red[256];
    red[tid] = acc; __syncthreads();
    for (int off = 128; off > 0; off >>= 1) {
        if (tid < off) red[tid] += red[tid+off];
        __syncthreads();
    }
    if (tid == 0) aux[0] = red[0];
}

// h1 = sin(h1) * h3, elementwise
__global__ __launch_bounds__(256) void sinmul_kernel(
    float* __restrict__ h1, const float* __restrict__ h3)
{
    const long i = (long)blockIdx.x * 256 + threadIdx.x;
    h1[i] = sinf(h1[i]) * h3[i];
}

// out (+)= combine[b,s,e] * out_e
template<bool FIRST>
__global__ __launch_bounds__(256) void moe_comb_kernel(
    const float* __restrict__ oe, const float* __restrict__ combine,
    int e, float* __restrict__ out)
{
    const long i = (long)blockIdx.x * 256 + threadIdx.x;
    const long row = i >> 10;
    const float v = combine[row*4 + e] * oe[i];
    if (FIRST) out[i] = v; else out[i] += v;
}

// ---------------------------------------------------------------------------
extern "C" void kernel_launch(void* const* d_in, const int* in_sizes, int n_in,
                              void* d_out, int out_size, void* d_ws, size_t ws_size,
                              hipStream_t stream)
{
    const float* x     = (const float*)d_in[0];
    // d_in[1] = freqs_cis (unused)
    const float* adaln = (const float*)d_in[2];
    const float* wq    = (const float*)d_in[3];
    const float* wk    = (const float*)d_in[4];
    const float* wv    = (const float*)d_in[5];
    const float* wo    = (const float*)d_in[6];
    const float* qn_w  = (const float*)d_in[7];
    const float* qn_b  = (const float*)d_in[8];
    const float* kn_w  = (const float*)d_in[9];
    const float* kn_b  = (const float*)d_in[10];
    const float* an_w  = (const float*)d_in[11];
    const float* an_b  = (const float*)d_in[12];
    const float* fn_w  = (const float*)d_in[13];
    const float* fn_b  = (const float*)d_in[14];
    const float* w1    = (const float*)d_in[15];
    const float* w2    = (const float*)d_in[16];
    const float* w3    = (const float*)d_in[17];
    const float* rw    = (const float*)d_in[18];
    const float* rb    = (const float*)d_in[19];
    const float* aw    = (const float*)d_in[20];
    const float* ab    = (const float*)d_in[21];
    float* out = (float*)d_out;
    float* ws  = (float*)d_ws;

    const long NTOK = (long)BB * SS;          // 4096 rows
    const long NBUF = NTOK * DD;              // 4194304 per big buffer
    const long NBAT = (long)SS * DD;          // per-batch matrix stride 1048576

    float* ada     = ws;                       // 24576
    float* gA      = ws + 24576;               // h / h2
    float* gB      = gA + NBUF;                // q / proj
    float* gC      = gB + NBUF;                // k / x2
    float* gD      = gC + NBUF;                // v / h1 chunk
    float* gE      = gD + NBUF;                // scores / attn / h3 chunk
    float* gF      = gE + NBUF;                // attn_out / out_e
    float* logits  = gF + NBUF;                // 16384
    float* probs   = logits + NTOK*EE;         // 16384
    float* combine = probs  + NTOK*EE;         // 16384
    float* nrm     = combine + NTOK*EE;        // 16

    const dim3 blk(256);

    // 1. adaLN vector
    ada_kernel<<<dim3(SIXD/256, BB), blk, 0, stream>>>(adaln, aw, ab, ada);

    // 2. h = modulate(ln(x))  (scale_msa @1024, shift_msa @0)
    ln_kernel<true><<<NTOK, blk, 0, stream>>>(x, an_w, an_b, ada, 1024, 0, gA, 1e-5f);

    // 3. q,k,v projections (NN, M=4096,K=1024,N=1024)
    gemm64<0,false><<<dim3(16,64,1), blk, 0, stream>>>(gA, wq, gB, 4096,1024,1024, 1024,1024,1024, 0,0,0);
    gemm64<0,false><<<dim3(16,64,1), blk, 0, stream>>>(gA, wk, gC, 4096,1024,1024, 1024,1024,1024, 0,0,0);
    gemm64<0,false><<<dim3(16,64,1), blk, 0, stream>>>(gA, wv, gD, 4096,1024,1024, 1024,1024,1024, 0,0,0);

    // 4. q_norm / k_norm (in place)
    ln_kernel<false><<<NTOK, blk, 0, stream>>>(gB, qn_w, qn_b, ada, 0, 0, gB, 1e-5f);
    ln_kernel<false><<<NTOK, blk, 0, stream>>>(gC, kn_w, kn_b, ada, 0, 0, gC, 1e-5f);

    // 5. scores[b,d,e] = sum_s q[b,s,d] k[b,s,e]  (TN, batched over b)
    gemm64<1,false><<<dim3(16,16,BB), blk, 0, stream>>>(gB, gC, gE, 1024,1024,1024, 1024,1024,1024, NBAT, NBAT, NBAT);

    // 6. softmax over last dim (4096 rows of 1024)
    softmax1024<<<NTOK, blk, 0, stream>>>(gE);

    // 7. out[b,s,d] = sum_e v[b,s,e] attn[b,d,e]  (NT, batched)
    gemm64<2,false><<<dim3(16,16,BB), blk, 0, stream>>>(gD, gE, gF, 1024,1024,1024, 1024,1024,1024, NBAT, NBAT, NBAT);

    // 8. proj = out @ wo (NN)
    gemm64<0,false><<<dim3(16,64,1), blk, 0, stream>>>(gF, wo, gB, 4096,1024,1024, 1024,1024,1024, 0,0,0);

    // 9. x2 = x + gate_msa * proj
    resgate_kernel<<<NBUF/256, blk, 0, stream>>>(x, gB, ada, gC);

    // 10. h2 = modulate(ln(x2))  (scale_mlp @4096, shift_mlp @3072)
    ln_kernel<true><<<NTOK, blk, 0, stream>>>(gC, fn_w, fn_b, ada, 4096, 3072, gA, 1e-5f);

    // 11. router
    router_logits_kernel<<<NTOK, blk, 0, stream>>>(gA, rw, rb, logits);
    router_norm_kernel<<<BB*EE, blk, 0, stream>>>(logits, nrm);
    router_post_kernel<<<NTOK/256, blk, 0, stream>>>(logits, nrm, probs, combine);
    aux_kernel<<<1, blk, 0, stream>>>(probs, out + NBUF);

    // 12. MoE: dense over experts, HID chunked by 704
    for (int e = 0; e < EE; ++e) {
        for (int c = 0; c < HID/HC; ++c) {
            const float* w1p = w1 + (long)e * DD * HID + (long)c * HC;
            const float* w3p = w3 + (long)e * DD * HID + (long)c * HC;
            const float* w2p = w2 + (long)e * HID * DD + (long)c * HC * DD;
            // h1c = h2 @ w1[:, chunk] ; h3c = h2 @ w3[:, chunk]
            gemm64<0,false><<<dim3(HC/64,64,1), blk, 0, stream>>>(gA, w1p, gD, 4096,HC,1024, 1024,HID,HC, 0,0,0);
            gemm64<0,false><<<dim3(HC/64,64,1), blk, 0, stream>>>(gA, w3p, gE, 4096,HC,1024, 1024,HID,HC, 0,0,0);
            // h1c = sin(h1c) * h3c
            sinmul_kernel<<<(NTOK*HC)/256, blk, 0, stream>>>(gD, gE);
            // out_e (+)= h1c @ w2[chunk, :]
            if (c == 0)
                gemm64<0,false><<<dim3(16,64,1), blk, 0, stream>>>(gD, w2p, gF, 4096,1024,HC, HC,1024,1024, 0,0,0);
            else
                gemm64<0,true><<<dim3(16,64,1), blk, 0, stream>>>(gD, w2p, gF, 4096,1024,HC, HC,1024,1024, 0,0,0);
        }
        // accumulate combine[b,s,e] * out_e into d_out
        if (e == 0) moe_comb_kernel<true ><<<NBUF/256, blk, 0, stream>>>(gF, combine, e, out);
        else        moe_comb_kernel<false><<<NBUF/256, blk, 0, stream>>>(gF, combine, e, out);
    }
}

// Round 2
// 2714.075 us; speedup vs baseline: 2.5704x; 2.5704x over previous
//
#include <hip/hip_runtime.h>
#include <hip/hip_bf16.h>
#include <math.h>

// Problem constants
#define BB 4
#define SS 1024
#define DD 1024
#define EE 4
#define HID 2816
#define HC 1408         // HID chunk (2816 = 2*1408), multiple of 128
#define SIXD 6144

typedef __bf16 v8bf __attribute__((ext_vector_type(8)));
typedef float  v4f  __attribute__((ext_vector_type(4)));

__device__ __forceinline__ ushort f2bf(float f) {
    union { float f; unsigned u; } v; v.f = f;
    unsigned r = v.u + 0x7fff + ((v.u >> 16) & 1);   // RNE
    return (ushort)(r >> 16);
}
__device__ __forceinline__ float bf2f(ushort u) {
    union { unsigned u; float f; } v; v.u = ((unsigned)u) << 16;
    return v.f;
}
__device__ __forceinline__ void split_bf(float x, ushort& h, ushort& l) {
    h = f2bf(x);
    l = f2bf(x - bf2f(h));
}
__device__ __forceinline__ void gload16(const void* g, void* l) {
    __builtin_amdgcn_global_load_lds((const __attribute__((address_space(1))) void*)g,
                                     (__attribute__((address_space(3))) void*)l, 16, 0, 0);
}

// ---------------------------------------------------------------------------
// MFMA GEMM: C[M][N] = A[M][K] * B^T where B stored [N][K]; both operands bf16.
// 128x128 tile, BK=32, 256 threads (4 waves), each wave 64x64 via 4x4 MFMAs.
// SPLIT: A,B given as hi+lo bf16 pairs; acc = Ah*Bh + Ah*Bl + Al*Bh.
// EPI: 0 = fp32 store; 2 = resgate (x + gate_msa*val) fp32; 3 = bf16(sin(f1)*val);
//      4 = out (+)= combine[row*4+i1]*val (i2 !=0 -> first write);
//      5 = split store (hi->Cv, lo->C2)
// Batched via blockIdx.z with element strides sA,sB,sC.
// ---------------------------------------------------------------------------
template<int EPI, bool SPLIT>
__global__ __launch_bounds__(256) void mgemm(
    const ushort* __restrict__ Ah, const ushort* __restrict__ Al,
    const ushort* __restrict__ Bh, const ushort* __restrict__ Bl,
    void* __restrict__ Cv, ushort* __restrict__ C2,
    const float* __restrict__ f1, const float* __restrict__ f2,
    int i1, int i2,
    int K, int lda, int ldb, int ldc,
    long sA, long sB, long sC)
{
    __shared__ __align__(16) ushort smem[(SPLIT ? 4 : 2) * 4096];
    ushort* As_h = smem;
    ushort* Bs_h = smem + 4096;
    ushort* As_l = SPLIT ? smem + 8192  : nullptr;
    ushort* Bs_l = SPLIT ? smem + 12288 : nullptr;

    const int tid  = threadIdx.x;
    const int wave = tid >> 6, lane = tid & 63;
    const int m0 = blockIdx.y * 128, n0 = blockIdx.x * 128;
    const long zA = (long)blockIdx.z * sA;
    const long zB = (long)blockIdx.z * sB;
    const long zC = (long)blockIdx.z * sC;

    const int srow = lane >> 2;          // 0..15
    const int skq  = (lane & 3) * 8;     // 0,8,16,24
    const int lm   = lane & 15;
    const int q8   = (lane >> 4) * 8;
    const int wm   = (wave >> 1) * 64, wn = (wave & 1) * 64;

    v4f acc[4][4];
    const v4f vzero = {0.f, 0.f, 0.f, 0.f};
    #pragma unroll
    for (int i = 0; i < 4; ++i)
        #pragma unroll
        for (int j = 0; j < 4; ++j) acc[i][j] = vzero;

    for (int k0 = 0; k0 < K; k0 += 32) {
        #pragma unroll
        for (int c = 0; c < 2; ++c) {
            const int row = c * 64 + wave * 16 + srow;
            const int loff = (c * 64 + wave * 16) * 32;
            gload16(Ah + zA + (long)(m0 + row) * lda + k0 + skq, As_h + loff);
            gload16(Bh + zB + (long)(n0 + row) * ldb + k0 + skq, Bs_h + loff);
            if (SPLIT) {
                gload16(Al + zA + (long)(m0 + row) * lda + k0 + skq, As_l + loff);
                gload16(Bl + zB + (long)(n0 + row) * ldb + k0 + skq, Bs_l + loff);
            }
        }
        __syncthreads();
        v8bf a[4], b[4];
        #pragma unroll
        for (int i = 0; i < 4; ++i) a[i] = *(const v8bf*)(As_h + (wm + 16*i + lm) * 32 + q8);
        #pragma unroll
        for (int j = 0; j < 4; ++j) b[j] = *(const v8bf*)(Bs_h + (wn + 16*j + lm) * 32 + q8);
        #pragma unroll
        for (int i = 0; i < 4; ++i)
            #pragma unroll
            for (int j = 0; j < 4; ++j)
                acc[i][j] = __builtin_amdgcn_mfma_f32_16x16x32_bf16(a[i], b[j], acc[i][j], 0, 0, 0);
        if (SPLIT) {
            v8bf al[4], bl[4];
            #pragma unroll
            for (int i = 0; i < 4; ++i) al[i] = *(const v8bf*)(As_l + (wm + 16*i + lm) * 32 + q8);
            #pragma unroll
            for (int j = 0; j < 4; ++j) bl[j] = *(const v8bf*)(Bs_l + (wn + 16*j + lm) * 32 + q8);
            #pragma unroll
            for (int i = 0; i < 4; ++i)
                #pragma unroll
                for (int j = 0; j < 4; ++j) {
                    acc[i][j] = __builtin_amdgcn_mfma_f32_16x16x32_bf16(a[i],  bl[j], acc[i][j], 0, 0, 0);
                    acc[i][j] = __builtin_amdgcn_mfma_f32_16x16x32_bf16(al[i], b[j],  acc[i][j], 0, 0, 0);
                }
        }
        __syncthreads();
    }

    const int r0 = (lane >> 4) * 4;
    #pragma unroll
    for (int i = 0; i < 4; ++i) {
        #pragma unroll
        for (int j = 0; j < 4; ++j) {
            const int colg = n0 + wn + 16*j + lm;
            #pragma unroll
            for (int r = 0; r < 4; ++r) {
                const long rowg = (long)(m0 + wm + 16*i + r0 + r);
                const long idx  = zC + rowg * ldc + colg;
                const float val = acc[i][j][r];
                if (EPI == 0) {
                    ((float*)Cv)[idx] = val;
                } else if (EPI == 2) {
                    ((float*)Cv)[idx] = f1[idx] + f2[(rowg >> 10) * SIXD + 2048 + colg] * val;
                } else if (EPI == 3) {
                    ((ushort*)Cv)[idx] = f2bf(sinf(f1[idx]) * val);
                } else if (EPI == 4) {
                    const float cmb = f1[rowg * 4 + i1];
                    float* o = (float*)Cv;
                    if (i2) o[idx] = cmb * val; else o[idx] += cmb * val;
                } else if (EPI == 5) {
                    ushort h, l; split_bf(val, h, l);
                    ((ushort*)Cv)[idx] = h;
                    C2[idx] = l;
                }
            }
        }
    }
}

// ---------------------------------------------------------------------------
// Transpose fp32 [K][N] (row stride ldin) -> bf16 [N][K] (row stride ldout),
// optionally split hi/lo. 64x64 tiles; grid (N/64, K/64, batches).
// ---------------------------------------------------------------------------
template<bool SP>
__global__ __launch_bounds__(256) void transp(
    const float* __restrict__ in, ushort* __restrict__ oh, ushort* __restrict__ ol,
    int ldin, int ldout, long sIn, long sOut)
{
    __shared__ float T[64][65];
    const int n0 = blockIdx.x * 64, k0 = blockIdx.y * 64;
    in += (long)blockIdx.z * sIn;
    oh += (long)blockIdx.z * sOut;
    if (SP) ol += (long)blockIdx.z * sOut;
    const int t = threadIdx.x;
    const int rr = t >> 4, c4 = (t & 15) * 4;
    #pragma unroll
    for (int p = 0; p < 4; ++p) {
        const int r = rr + p * 16;
        const float4 v = *(const float4*)(in + (long)(k0 + r) * ldin + n0 + c4);
        T[c4+0][r] = v.x; T[c4+1][r] = v.y; T[c4+2][r] = v.z; T[c4+3][r] = v.w;
    }
    __syncthreads();
    #pragma unroll
    for (int p = 0; p < 4; ++p) {
        const int idx = t + 256 * p;
        const int n = idx >> 4, c = (idx & 15) * 4;
        ushort4 wh, wl;
        float x0 = T[n][c], x1 = T[n][c+1], x2 = T[n][c+2], x3 = T[n][c+3];
        if (SP) {
            split_bf(x0, wh.x, wl.x); split_bf(x1, wh.y, wl.y);
            split_bf(x2, wh.z, wl.z); split_bf(x3, wh.w, wl.w);
        } else {
            wh.x = f2bf(x0); wh.y = f2bf(x1); wh.z = f2bf(x2); wh.w = f2bf(x3);
        }
        *(ushort4*)(oh + (long)(n0 + n) * ldout + k0 + c) = wh;
        if (SP) *(ushort4*)(ol + (long)(n0 + n) * ldout + k0 + c) = wl;
    }
}

// ---------------------------------------------------------------------------
// adaLN: ada[b,n] = sum_k silu(adaln[b,k]) * ada_w[k,n] + ada_b[n]
// ---------------------------------------------------------------------------
__global__ __launch_bounds__(256) void ada_kernel(
    const float* __restrict__ adaln, const float* __restrict__ aw,
    const float* __restrict__ ab, float* __restrict__ ada)
{
    __shared__ float s[DD];
    const int b = blockIdx.y;
    const int tid = threadIdx.x;
    for (int i = tid; i < DD; i += 256) {
        const float v = adaln[(long)b * DD + i];
        s[i] = v / (1.f + expf(-v));
    }
    __syncthreads();
    const int n = blockIdx.x * 256 + tid;
    float acc = 0.f;
    for (int k = 0; k < DD; ++k) acc += s[k] * aw[(long)k * SIXD + n];
    ada[(long)b * SIXD + n] = acc + ab[n];
}

// ---------------------------------------------------------------------------
// LayerNorm over D=1024, optional adaLN modulate.
// OUT: 0 = fp32, 1 = split bf16 hi/lo, 2 = bf16
// ---------------------------------------------------------------------------
template<int OUT, bool MOD>
__global__ __launch_bounds__(256) void ln_kernel(
    const float* __restrict__ x, const float* __restrict__ w, const float* __restrict__ bias,
    const float* __restrict__ ada, int scale_off, int shift_off,
    float* __restrict__ o32, ushort* __restrict__ oh, ushort* __restrict__ ol, float eps)
{
    const int row = blockIdx.x;
    const int b = row >> 10;
    const int tid = threadIdx.x;
    const float* xr = x + (long)row * DD;
    float v[4]; float s = 0.f, q = 0.f;
    #pragma unroll
    for (int i = 0; i < 4; ++i) { v[i] = xr[tid + 256*i]; s += v[i]; q += v[i]*v[i]; }
    __shared__ float rs_[256], rq_[256];
    rs_[tid] = s; rq_[tid] = q; __syncthreads();
    for (int off = 128; off > 0; off >>= 1) {
        if (tid < off) { rs_[tid] += rs_[tid+off]; rq_[tid] += rq_[tid+off]; }
        __syncthreads();
    }
    const float mu  = rs_[0] * (1.f/DD);
    const float var = rq_[0] * (1.f/DD) - mu*mu;
    const float rstd = rsqrtf(var + eps);
    const float* ar = ada + (long)b * SIXD;
    #pragma unroll
    for (int i = 0; i < 4; ++i) {
        const int d = tid + 256*i;
        float y = (v[i] - mu) * rstd * w[d] + bias[d];
        if (MOD) y = y * (1.f + ar[scale_off + d]) + ar[shift_off + d];
        const long idx = (long)row * DD + d;
        if (OUT == 0) o32[idx] = y;
        else if (OUT == 1) { ushort h, l; split_bf(y, h, l); oh[idx] = h; ol[idx] = l; }
        else oh[idx] = f2bf(y);
    }
}

// ---------------------------------------------------------------------------
// Row softmax over 1024 -> split bf16 hi/lo
// ---------------------------------------------------------------------------
__global__ __launch_bounds__(256) void softmax_split(
    const float* __restrict__ in, ushort* __restrict__ oh, ushort* __restrict__ ol)
{
    const long row = blockIdx.x;
    const float* p = in + row * 1024;
    const int tid = threadIdx.x;
    float v[4]; float mx = -INFINITY;
    #pragma unroll
    for (int i = 0; i < 4; ++i) { v[i] = p[tid + 256*i]; mx = fmaxf(mx, v[i]); }
    __shared__ float red[256];
    red[tid] = mx; __syncthreads();
    for (int off = 128; off > 0; off >>= 1) {
        if (tid < off) red[tid] = fmaxf(red[tid], red[tid+off]);
        __syncthreads();
    }
    const float rowmax = red[0];
    __syncthreads();
    float s = 0.f;
    #pragma unroll
    for (int i = 0; i < 4; ++i) { v[i] = expf(v[i] - rowmax); s += v[i]; }
    red[tid] = s; __syncthreads();
    for (int off = 128; off > 0; off >>= 1) {
        if (tid < off) red[tid] += red[tid+off];
        __syncthreads();
    }
    const float inv = 1.f / red[0];
    #pragma unroll
    for (int i = 0; i < 4; ++i) {
        ushort h, l; split_bf(v[i] * inv, h, l);
        oh[row*1024 + tid + 256*i] = h;
        ol[row*1024 + tid + 256*i] = l;
    }
}

// ---------------------------------------------------------------------------
// Fused: h2 = modulate(ln(x2)) in fp32, logits[row,e] = h2 . rw[:,e] + rb[e]
// (fp32 end-to-end so router top-2 matches the reference exactly)
// ---------------------------------------------------------------------------
__global__ __launch_bounds__(256) void router_fused(
    const float* __restrict__ x2, const float* __restrict__ fw, const float* __restrict__ fb,
    const float* __restrict__ ada, const float* __restrict__ rw, const float* __restrict__ rb,
    float* __restrict__ logits)
{
    const int row = blockIdx.x;
    const int b = row >> 10;
    const int tid = threadIdx.x;
    const float* xr = x2 + (long)row * DD;
    float v[4]; float s = 0.f, q = 0.f;
    #pragma unroll
    for (int i = 0; i < 4; ++i) { v[i] = xr[tid + 256*i]; s += v[i]; q += v[i]*v[i]; }
    __shared__ float rs_[256], rq_[256];
    rs_[tid] = s; rq_[tid] = q; __syncthreads();
    for (int off = 128; off > 0; off >>= 1) {
        if (tid < off) { rs_[tid] += rs_[tid+off]; rq_[tid] += rq_[tid+off]; }
        __syncthreads();
    }
    const float mu  = rs_[0] * (1.f/DD);
    const float var = rq_[0] * (1.f/DD) - mu*mu;
    const float rstd = rsqrtf(var + 1e-5f);
    const float* ar = ada + (long)b * SIXD;
    float acc[4] = {0.f, 0.f, 0.f, 0.f};
    #pragma unroll
    for (int i = 0; i < 4; ++i) {
        const int d = tid + 256*i;
        float h = (v[i] - mu) * rstd * fw[d] + fb[d];
        h = h * (1.f + ar[4096 + d]) + ar[3072 + d];
        const float* r4 = rw + (long)d * 4;
        acc[0] += h*r4[0]; acc[1] += h*r4[1]; acc[2] += h*r4[2]; acc[3] += h*r4[3];
    }
    __syncthreads();
    __shared__ float red[256];
    for (int e = 0; e < EE; ++e) {
        red[tid] = acc[e]; __syncthreads();
        for (int off = 128; off > 0; off >>= 1) {
            if (tid < off) red[tid] += red[tid+off];
            __syncthreads();
        }
        if (tid == 0) logits[(long)row * EE + e] = red[0] + rb[e];
        __syncthreads();
    }
}

// L2 norm along sequence dim: one block per (b,e)
__global__ __launch_bounds__(256) void router_norm_kernel(
    const float* __restrict__ logits, float* __restrict__ nrm)
{
    const int b = blockIdx.x >> 2, e = blockIdx.x & 3;
    const int tid = threadIdx.x;
    float s = 0.f;
    for (int si = tid; si < SS; si += 256) {
        const float v = logits[((long)b * SS + si) * EE + e];
        s += v * v;
    }
    __shared__ float red[256];
    red[tid] = s; __syncthreads();
    for (int off = 128; off > 0; off >>= 1) {
        if (tid < off) red[tid] += red[tid+off];
        __syncthreads();
    }
    if (tid == 0) nrm[blockIdx.x] = sqrtf(red[0]);
}

__global__ __launch_bounds__(256) void router_post_kernel(
    const float* __restrict__ logits, const float* __restrict__ nrm,
    float* __restrict__ probs, float* __restrict__ combine)
{
    const long row = (long)blockIdx.x * 256 + threadIdx.x;
    const int b = (int)(row >> 10);
    float l[4], p[4];
    #pragma unroll
    for (int e = 0; e < 4; ++e)
        l[e] = logits[row*4 + e] / fmaxf(nrm[b*4 + e], 1e-12f);
    const float mx = fmaxf(fmaxf(l[0], l[1]), fmaxf(l[2], l[3]));
    float s = 0.f;
    #pragma unroll
    for (int e = 0; e < 4; ++e) { p[e] = expf(l[e] - mx); s += p[e]; }
    const float inv = 1.f / s;
    #pragma unroll
    for (int e = 0; e < 4; ++e) { p[e] *= inv; probs[row*4 + e] = p[e]; }
    int i1 = 0;
    #pragma unroll
    for (int e = 1; e < 4; ++e) if (p[e] > p[i1]) i1 = e;
    int i2 = (i1 == 0) ? 1 : 0;
    #pragma unroll
    for (int e = 0; e < 4; ++e) if (e != i1 && p[e] > p[i2]) i2 = e;
    float c[4] = {0.f, 0.f, 0.f, 0.f};
    c[i1] = p[i1]; c[i2] = p[i2];
    #pragma unroll
    for (int e = 0; e < 4; ++e) combine[row*4 + e] = c[e];
}

__global__ __launch_bounds__(256) void aux_kernel(
    const float* __restrict__ probs, float* __restrict__ aux)
{
    const int tid = threadIdx.x;
    float acc = 0.f;
    for (int i = tid; i < SS*EE; i += 256) {
        const float avg = 0.25f * (probs[i] + probs[SS*EE + i] +
                                   probs[2*SS*EE + i] + probs[3*SS*EE + i]);
        const float d = 0.25f - avg;
        acc += d * d;
    }
    __shared__ float red[256];
    red[tid] = acc; __syncthreads();
    for (int off = 128; off > 0; off >>= 1) {
        if (tid < off) red[tid] += red[tid+off];
        __syncthreads();
    }
    if (tid == 0) aux[0] = red[0];
}

// ---------------------------------------------------------------------------
extern "C" void kernel_launch(void* const* d_in, const int* in_sizes, int n_in,
                              void* d_out, int out_size, void* d_ws, size_t ws_size,
                              hipStream_t stream)
{
    (void)in_sizes; (void)n_in; (void)out_size; (void)ws_size;
    const float* x     = (const float*)d_in[0];
    const float* adaln = (const float*)d_in[2];
    const float* wq    = (const float*)d_in[3];
    const float* wk    = (const float*)d_in[4];
    const float* wv    = (const float*)d_in[5];
    const float* wo    = (const float*)d_in[6];
    const float* qn_w  = (const float*)d_in[7];
    const float* qn_b  = (const float*)d_in[8];
    const float* kn_w  = (const float*)d_in[9];
    const float* kn_b  = (const float*)d_in[10];
    const float* an_w  = (const float*)d_in[11];
    const float* an_b  = (const float*)d_in[12];
    const float* fn_w  = (const float*)d_in[13];
    const float* fn_b  = (const float*)d_in[14];
    const float* w1    = (const float*)d_in[15];
    const float* w2    = (const float*)d_in[16];
    const float* w3    = (const float*)d_in[17];
    const float* rw    = (const float*)d_in[18];
    const float* rb    = (const float*)d_in[19];
    const float* aw    = (const float*)d_in[20];
    const float* ab    = (const float*)d_in[21];
    float* out = (float*)d_out;

    const long NBAT = (long)SS * DD;          // 1048576
    const long R16M = 16777216;               // 16 MiB region

    // Arena: [ada | G | E | D | A | B | C | smalls]  (A,B adjacent for h1f)
    char* base = (char*)d_ws;
    float*  ada  = (float*)base;                  // 98,304 B
    char* G = base + 98304;
    char* E = G + R16M;
    char* D = E + R16M;
    char* A = D + R16M;
    char* B = A + R16M;
    char* C = B + R16M;
    float* logits  = (float*)(C + R16M);
    float* probs   = logits + 16384;
    float* comb    = probs  + 16384;
    float* nrm     = comb   + 16384;

    // G: attention weight transposes (8 x 2MB), later MoE chunk weights
    ushort* wqT_h = (ushort*)G;           ushort* wqT_l = wqT_h + 1048576;
    ushort* wkT_h = wqT_l + 1048576;      ushort* wkT_l = wkT_h + 1048576;
    ushort* wvT_h = wkT_l + 1048576;      ushort* wvT_l = wvT_h + 1048576;
    ushort* woT_h = wvT_l + 1048576;      ushort* woT_l = woT_h + 1048576;
    ushort* w1Tc  = (ushort*)G;                        // [1408][1024]
    ushort* w3Tc  = w1Tc + 1408*1024;
    ushort* w2Tc  = w3Tc + 1408*1024;                  // [1024][1408]
    // E: kT hi/lo -> h2 bf16
    ushort* kT_h = (ushort*)E; ushort* kT_l = kT_h + 4194304;
    ushort* h2bf = (ushort*)E;
    // D: v hi/lo -> x2 fp32 -> act bf16
    ushort* v_h = (ushort*)D; ushort* v_l = v_h + 4194304;
    float*  x2  = (float*)D;
    ushort* actb = (ushort*)D;                         // [4096][1408]
    // A: h hi/lo -> qT hi/lo -> h1f (spans A+B)
    ushort* h_h = (ushort*)A; ushort* h_l = h_h + 4194304;
    ushort* qT_h = (ushort*)A; ushort* qT_l = qT_h + 4194304;
    float*  h1f = (float*)A;                           // [4096][1408]
    // B: q32 -> attn hi/lo
    float*  q32 = (float*)B;
    ushort* at_h = (ushort*)B; ushort* at_l = at_h + 4194304;
    // C: k32 -> scores fp32 -> ao hi/lo
    float*  k32 = (float*)C;
    float*  sc  = (float*)C;
    ushort* ao_h = (ushort*)C; ushort* ao_l = ao_h + 4194304;

    const dim3 blk(256);

    // 1. adaLN vector
    ada_kernel<<<dim3(SIXD/256, BB), blk, 0, stream>>>(adaln, aw, ab, ada);

    // 2. attention weight prep: transpose + hi/lo split
    transp<true><<<dim3(16,16,1), blk, 0, stream>>>(wq, wqT_h, wqT_l, 1024, 1024, 0, 0);
    transp<true><<<dim3(16,16,1), blk, 0, stream>>>(wk, wkT_h, wkT_l, 1024, 1024, 0, 0);
    transp<true><<<dim3(16,16,1), blk, 0, stream>>>(wv, wvT_h, wvT_l, 1024, 1024, 0, 0);
    transp<true><<<dim3(16,16,1), blk, 0, stream>>>(wo, woT_h, woT_l, 1024, 1024, 0, 0);

    // 3. h = modulate(ln(x)) -> split bf16
    ln_kernel<1,true><<<4096, blk, 0, stream>>>(x, an_w, an_b, ada, 1024, 0,
                                                nullptr, h_h, h_l, 1e-5f);

    // 4. q,k,v projections (split-precision MFMA)
    mgemm<0,true><<<dim3(8,32,1), blk, 0, stream>>>(h_h, h_l, wqT_h, wqT_l, q32, nullptr,
        nullptr, nullptr, 0, 0, 1024, 1024, 1024, 1024, 0, 0, 0);
    mgemm<0,true><<<dim3(8,32,1), blk, 0, stream>>>(h_h, h_l, wkT_h, wkT_l, k32, nullptr,
        nullptr, nullptr, 0, 0, 1024, 1024, 1024, 1024, 0, 0, 0);
    mgemm<5,true><<<dim3(8,32,1), blk, 0, stream>>>(h_h, h_l, wvT_h, wvT_l, v_h, v_l,
        nullptr, nullptr, 0, 0, 1024, 1024, 1024, 1024, 0, 0, 0);

    // 5. q_norm / k_norm (fp32, in place)
    ln_kernel<0,false><<<4096, blk, 0, stream>>>(q32, qn_w, qn_b, ada, 0, 0, q32, nullptr, nullptr, 1e-5f);
    ln_kernel<0,false><<<4096, blk, 0, stream>>>(k32, kn_w, kn_b, ada, 0, 0, k32, nullptr, nullptr, 1e-5f);

    // 6. transpose q,k to [b][d][s] with hi/lo split
    transp<true><<<dim3(16,16,BB), blk, 0, stream>>>(q32, qT_h, qT_l, 1024, 1024, NBAT, NBAT);
    transp<true><<<dim3(16,16,BB), blk, 0, stream>>>(k32, kT_h, kT_l, 1024, 1024, NBAT, NBAT);

    // 7. scores[b,d,e] = sum_s qT[b,d,s]*kT[b,e,s]  (split MFMA, batched)
    mgemm<0,true><<<dim3(8,8,BB), blk, 0, stream>>>(qT_h, qT_l, kT_h, kT_l, sc, nullptr,
        nullptr, nullptr, 0, 0, 1024, 1024, 1024, 1024, NBAT, NBAT, NBAT);

    // 8. softmax rows -> attn hi/lo
    softmax_split<<<4096, blk, 0, stream>>>(sc, at_h, at_l);

    // 9. ao[b,s,d] = sum_e v[b,s,e]*attn[b,d,e]  (split MFMA, batched) -> split out
    mgemm<5,true><<<dim3(8,8,BB), blk, 0, stream>>>(v_h, v_l, at_h, at_l, ao_h, ao_l,
        nullptr, nullptr, 0, 0, 1024, 1024, 1024, 1024, NBAT, NBAT, NBAT);

    // 10. x2 = x + gate_msa * (ao @ wo)   (split MFMA, fused resgate)
    mgemm<2,true><<<dim3(8,32,1), blk, 0, stream>>>(ao_h, ao_l, woT_h, woT_l, x2, nullptr,
        x, ada, 0, 0, 1024, 1024, 1024, 1024, 0, 0, 0);

    // 11. h2 = modulate(ln(x2)) -> bf16 (MoE input)
    ln_kernel<2,true><<<4096, blk, 0, stream>>>(x2, fn_w, fn_b, ada, 4096, 3072,
                                                nullptr, h2bf, nullptr, 1e-5f);

    // 12. router: fp32 logits from x2 (exact top-2), norm, post, aux
    router_fused<<<4096, blk, 0, stream>>>(x2, fn_w, fn_b, ada, rw, rb, logits);
    router_norm_kernel<<<BB*EE, blk, 0, stream>>>(logits, nrm);
    router_post_kernel<<<16, blk, 0, stream>>>(logits, nrm, probs, comb);
    aux_kernel<<<1, blk, 0, stream>>>(probs, out + (long)BB*SS*DD);

    // 13. MoE: dense over experts, plain bf16 MFMA, HID chunked by 1408
    for (int e = 0; e < EE; ++e) {
        for (int c = 0; c < HID/HC; ++c) {
            // chunk weight transposes
            transp<false><<<dim3(22,16,1), blk, 0, stream>>>(
                w1 + (long)e*DD*HID + (long)c*HC, w1Tc, nullptr, HID, 1024, 0, 0);
            transp<false><<<dim3(22,16,1), blk, 0, stream>>>(
                w3 + (long)e*DD*HID + (long)c*HC, w3Tc, nullptr, HID, 1024, 0, 0);
            transp<false><<<dim3(16,22,1), blk, 0, stream>>>(
                w2 + (long)e*HID*DD + (long)c*HC*DD, w2Tc, nullptr, DD, HC, 0, 0);
            // h1 = h2 @ w1c
            mgemm<0,false><<<dim3(11,32,1), blk, 0, stream>>>(h2bf, nullptr, w1Tc, nullptr,
                h1f, nullptr, nullptr, nullptr, 0, 0, 1024, 1024, 1024, HC, 0, 0, 0);
            // act = bf16( sin(h1) * (h2 @ w3c) )
            mgemm<3,false><<<dim3(11,32,1), blk, 0, stream>>>(h2bf, nullptr, w3Tc, nullptr,
                actb, nullptr, h1f, nullptr, 0, 0, 1024, 1024, 1024, HC, 0, 0, 0);
            // out (+)= combine[:,e] * (act @ w2c)
            mgemm<4,false><<<dim3(8,32,1), blk, 0, stream>>>(actb, nullptr, w2Tc, nullptr,
                out, nullptr, comb, nullptr, e, (e==0 && c==0) ? 1 : 0,
                HC, HC, HC, 1024, 0, 0, 0);
        }
    }
}

// Round 3
// 1016.012 us; speedup vs baseline: 6.8662x; 2.6713x over previous
//
#include <hip/hip_runtime.h>
#include <hip/hip_bf16.h>
#include <math.h>

// Problem constants
#define BB 4
#define SS 1024
#define DD 1024
#define EE 4
#define HID 2816
#define HC 1408         // HID chunk (2816 = 2*1408)
#define SIXD 6144
#define ESLOT 4224      // per-expert slot region (33*128 >= 4096 max tokens)
#define TSLOT 16896     // 4*ESLOT
#define MBLK 33         // m-blocks per expert (ESLOT/128)

typedef __bf16 v8bf __attribute__((ext_vector_type(8)));
typedef float  v4f  __attribute__((ext_vector_type(4)));

__device__ __forceinline__ ushort f2bf(float f) {
    union { float f; unsigned u; } v; v.f = f;
    unsigned r = v.u + 0x7fff + ((v.u >> 16) & 1);   // RNE
    return (ushort)(r >> 16);
}
__device__ __forceinline__ float bf2f(ushort u) {
    union { unsigned u; float f; } v; v.u = ((unsigned)u) << 16;
    return v.f;
}
__device__ __forceinline__ void split_bf(float x, ushort& h, ushort& l) {
    h = f2bf(x);
    l = f2bf(x - bf2f(h));
}
__device__ __forceinline__ void gload16(const void* g, void* l) {
    __builtin_amdgcn_global_load_lds((const __attribute__((address_space(1))) void*)g,
                                     (__attribute__((address_space(3))) void*)l, 16, 0, 0);
}
// wait until at most N vector-memory ops outstanding (vmcnt(N)); lgkm/exp untouched
template<int N> __device__ __forceinline__ void wait_vm() {
    __builtin_amdgcn_s_waitcnt((N & 15) | (0x7 << 4) | (0xF << 8) | ((N >> 4) << 14));
}

// ---------------------------------------------------------------------------
// MFMA GEMM, 128x128 tile, BK=32, 256 threads, double-buffered LDS with
// manual s_barrier + vmcnt(L) so next-tile global_load_lds stay in flight
// across the MFMA phase (one-deep software pipeline).
// C[M][N] = A[M][K] * B^T, B stored [N][K], bf16 operands.
// SPLIT: hi+lo pairs, 3 MFMA passes (AhBh + AhBl + AlBh).
// DUAL : two B operands (B and B2=Bl arg), two accumulators (for h1*h3 fuse).
// MOE  : m-blocks live in per-expert slot space with early-exit on count.
// GATHER: A rows gathered via tokidx (per-lane global addresses).
// EPI: 0 fp32 store | 2 resgate x+gate*val | 5 split bf16 store |
//      6 bf16(sin(acc)*acc2) store | 7 atomic scatter out += comb*val
// ---------------------------------------------------------------------------
template<int EPI, bool SPLIT, bool DUAL, bool MOE, bool GATHER>
__global__ __launch_bounds__(256, 2) void mgemm(
    const ushort* __restrict__ Ah, const ushort* __restrict__ Al,
    const ushort* __restrict__ Bh, const ushort* __restrict__ Bl,
    void* __restrict__ Cv, ushort* __restrict__ C2,
    const float* __restrict__ f1, const float* __restrict__ f2,
    const int* __restrict__ tokidx, const int* __restrict__ cnt,
    int K, int lda, int ldb, int ldc,
    long sA, long sB, long sC)
{
    constexpr int NARR = SPLIT ? 4 : (DUAL ? 3 : 2);
    constexpr int L = 2 * NARR;          // global_load_lds per thread per tile
    __shared__ __align__(16) ushort smem[2 * NARR * 4096];

    const int tid  = threadIdx.x;
    const int wave = tid >> 6, lane = tid & 63;
    const int n0 = blockIdx.x * 128;

    int eexp = 0, m0;
    if (MOE) {
        eexp = blockIdx.y / MBLK;
        const int mloc = (blockIdx.y % MBLK) * 128;
        if (mloc >= cnt[eexp]) return;            // empty block: uniform exit
        m0 = eexp * ESLOT + mloc;
    } else {
        m0 = blockIdx.y * 128;
    }
    const long zA = MOE ? 0 : (long)blockIdx.z * sA;
    const long zB = MOE ? (long)eexp * sB : (long)blockIdx.z * sB;
    const long zC = MOE ? 0 : (long)blockIdx.z * sC;

    const int srow = lane >> 2;          // 0..15
    const int skq  = (lane & 3) * 8;     // 0,8,16,24
    const int lm   = lane & 15;
    const int q8   = (lane >> 4) * 8;
    const int wm   = (wave >> 1) * 64, wn = (wave & 1) * 64;

    long arow[2];
    #pragma unroll
    for (int c = 0; c < 2; ++c) {
        const int r = c * 64 + wave * 16 + srow;
        if (GATHER) {
            const int t = tokidx[m0 + r];
            arow[c] = (t < 0) ? 0 : (long)t;
        } else arow[c] = m0 + r;
    }

    v4f acc[4][4], acc2[4][4];
    const v4f vzero = {0.f, 0.f, 0.f, 0.f};
    #pragma unroll
    for (int i = 0; i < 4; ++i)
        #pragma unroll
        for (int j = 0; j < 4; ++j) { acc[i][j] = vzero; if (DUAL) acc2[i][j] = vzero; }

    auto issue = [&](int kt, int st) {
        const long kk = (long)kt * 32 + skq;
        ushort* base = smem + st * (NARR * 4096);
        #pragma unroll
        for (int c = 0; c < 2; ++c) {
            const int rb   = c * 64 + wave * 16;
            const int row  = rb + srow;
            const int loff = rb * 32;
            gload16(Ah + zA + arow[c] * lda + kk, base + loff);
            gload16(Bh + zB + (long)(n0 + row) * ldb + kk, base + 4096 + loff);
            if (DUAL)
                gload16(Bl + zB + (long)(n0 + row) * ldb + kk, base + 8192 + loff);
            if (SPLIT) {
                gload16(Al + zA + arow[c] * lda + kk, base + 8192 + loff);
                gload16(Bl + zB + (long)(n0 + row) * ldb + kk, base + 12288 + loff);
            }
        }
    };

    const int nk = K / 32;
    issue(0, 0);
    for (int kt = 0; kt < nk; ++kt) {
        const int st = kt & 1;
        if (kt) __builtin_amdgcn_s_barrier();     // all waves done reading st^1
        const bool hasNext = (kt + 1 < nk);
        if (hasNext) issue(kt + 1, st ^ 1);
        if (hasNext) wait_vm<L>(); else wait_vm<0>();   // tile kt's loads landed
        __builtin_amdgcn_s_barrier();
        const ushort* As = smem + st * (NARR * 4096);
        v8bf a[4], b[4];
        #pragma unroll
        for (int i = 0; i < 4; ++i) a[i] = *(const v8bf*)(As + (wm + 16*i + lm) * 32 + q8);
        #pragma unroll
        for (int j = 0; j < 4; ++j) b[j] = *(const v8bf*)(As + 4096 + (wn + 16*j + lm) * 32 + q8);
        #pragma unroll
        for (int i = 0; i < 4; ++i)
            #pragma unroll
            for (int j = 0; j < 4; ++j)
                acc[i][j] = __builtin_amdgcn_mfma_f32_16x16x32_bf16(a[i], b[j], acc[i][j], 0, 0, 0);
        if (DUAL) {
            v8bf b2[4];
            #pragma unroll
            for (int j = 0; j < 4; ++j) b2[j] = *(const v8bf*)(As + 8192 + (wn + 16*j + lm) * 32 + q8);
            #pragma unroll
            for (int i = 0; i < 4; ++i)
                #pragma unroll
                for (int j = 0; j < 4; ++j)
                    acc2[i][j] = __builtin_amdgcn_mfma_f32_16x16x32_bf16(a[i], b2[j], acc2[i][j], 0, 0, 0);
        }
        if (SPLIT) {
            v8bf al[4], bl[4];
            #pragma unroll
            for (int i = 0; i < 4; ++i) al[i] = *(const v8bf*)(As + 8192 + (wm + 16*i + lm) * 32 + q8);
            #pragma unroll
            for (int j = 0; j < 4; ++j) bl[j] = *(const v8bf*)(As + 12288 + (wn + 16*j + lm) * 32 + q8);
            #pragma unroll
            for (int i = 0; i < 4; ++i)
                #pragma unroll
                for (int j = 0; j < 4; ++j) {
                    acc[i][j] = __builtin_amdgcn_mfma_f32_16x16x32_bf16(a[i],  bl[j], acc[i][j], 0, 0, 0);
                    acc[i][j] = __builtin_amdgcn_mfma_f32_16x16x32_bf16(al[i], b[j],  acc[i][j], 0, 0, 0);
                }
        }
    }

    const int r0 = (lane >> 4) * 4;
    if (EPI == 7) {
        #pragma unroll
        for (int i = 0; i < 4; ++i)
            #pragma unroll
            for (int r = 0; r < 4; ++r) {
                const int rowg = m0 + wm + 16*i + r0 + r;
                const int t = tokidx[rowg];
                if (t >= 0) {
                    const float cw = f1[t * 4 + eexp];
                    #pragma unroll
                    for (int j = 0; j < 4; ++j) {
                        const int colg = n0 + wn + 16*j + lm;
                        atomicAdd((float*)Cv + (long)t * 1024 + colg, cw * acc[i][j][r]);
                    }
                }
            }
    } else {
        #pragma unroll
        for (int i = 0; i < 4; ++i) {
            #pragma unroll
            for (int j = 0; j < 4; ++j) {
                const int colg = n0 + wn + 16*j + lm;
                #pragma unroll
                for (int r = 0; r < 4; ++r) {
                    const long rowg = (long)(m0 + wm + 16*i + r0 + r);
                    const long idx  = zC + rowg * ldc + colg;
                    const float val = acc[i][j][r];
                    if (EPI == 0) {
                        ((float*)Cv)[idx] = val;
                    } else if (EPI == 2) {
                        ((float*)Cv)[idx] = f1[idx] + f2[(rowg >> 10) * SIXD + 2048 + colg] * val;
                    } else if (EPI == 5) {
                        ushort h, l; split_bf(val, h, l);
                        ((ushort*)Cv)[idx] = h;
                        C2[idx] = l;
                    } else if (EPI == 6) {
                        ((ushort*)Cv)[idx] = f2bf(sinf(val) * acc2[i][j][r]);
                    }
                }
            }
        }
    }
}

// ---------------------------------------------------------------------------
// Transpose fp32 [K][N] (row stride ldin) -> bf16 [N][K] (row stride ldout),
// optionally split hi/lo. grid (N/64, K/64, batches).
// ---------------------------------------------------------------------------
template<bool SP>
__global__ __launch_bounds__(256) void transp(
    const float* __restrict__ in, ushort* __restrict__ oh, ushort* __restrict__ ol,
    int ldin, int ldout, long sIn, long sOut)
{
    __shared__ float T[64][65];
    const int n0 = blockIdx.x * 64, k0 = blockIdx.y * 64;
    in += (long)blockIdx.z * sIn;
    oh += (long)blockIdx.z * sOut;
    if (SP) ol += (long)blockIdx.z * sOut;
    const int t = threadIdx.x;
    const int rr = t >> 4, c4 = (t & 15) * 4;
    #pragma unroll
    for (int p = 0; p < 4; ++p) {
        const int r = rr + p * 16;
        const float4 v = *(const float4*)(in + (long)(k0 + r) * ldin + n0 + c4);
        T[c4+0][r] = v.x; T[c4+1][r] = v.y; T[c4+2][r] = v.z; T[c4+3][r] = v.w;
    }
    __syncthreads();
    #pragma unroll
    for (int p = 0; p < 4; ++p) {
        const int idx = t + 256 * p;
        const int n = idx >> 4, c = (idx & 15) * 4;
        ushort4 wh, wl;
        float x0 = T[n][c], x1 = T[n][c+1], x2 = T[n][c+2], x3 = T[n][c+3];
        if (SP) {
            split_bf(x0, wh.x, wl.x); split_bf(x1, wh.y, wl.y);
            split_bf(x2, wh.z, wl.z); split_bf(x3, wh.w, wl.w);
        } else {
            wh.x = f2bf(x0); wh.y = f2bf(x1); wh.z = f2bf(x2); wh.w = f2bf(x3);
        }
        *(ushort4*)(oh + (long)(n0 + n) * ldout + k0 + c) = wh;
        if (SP) *(ushort4*)(ol + (long)(n0 + n) * ldout + k0 + c) = wl;
    }
}

// ---------------------------------------------------------------------------
__global__ __launch_bounds__(256) void ada_kernel(
    const float* __restrict__ adaln, const float* __restrict__ aw,
    const float* __restrict__ ab, float* __restrict__ ada)
{
    __shared__ float s[DD];
    const int b = blockIdx.y;
    const int tid = threadIdx.x;
    for (int i = tid; i < DD; i += 256) {
        const float v = adaln[(long)b * DD + i];
        s[i] = v / (1.f + expf(-v));
    }
    __syncthreads();
    const int n = blockIdx.x * 256 + tid;
    float acc = 0.f;
    for (int k = 0; k < DD; ++k) acc += s[k] * aw[(long)k * SIXD + n];
    ada[(long)b * SIXD + n] = acc + ab[n];
}

// LayerNorm over D=1024; OUT: 0 fp32, 1 split bf16 hi/lo, 2 bf16
template<int OUT, bool MOD>
__global__ __launch_bounds__(256) void ln_kernel(
    const float* __restrict__ x, const float* __restrict__ w, const float* __restrict__ bias,
    const float* __restrict__ ada, int scale_off, int shift_off,
    float* __restrict__ o32, ushort* __restrict__ oh, ushort* __restrict__ ol, float eps)
{
    const int row = blockIdx.x;
    const int b = row >> 10;
    const int tid = threadIdx.x;
    const float* xr = x + (long)row * DD;
    float v[4]; float s = 0.f, q = 0.f;
    #pragma unroll
    for (int i = 0; i < 4; ++i) { v[i] = xr[tid + 256*i]; s += v[i]; q += v[i]*v[i]; }
    __shared__ float rs_[256], rq_[256];
    rs_[tid] = s; rq_[tid] = q; __syncthreads();
    for (int off = 128; off > 0; off >>= 1) {
        if (tid < off) { rs_[tid] += rs_[tid+off]; rq_[tid] += rq_[tid+off]; }
        __syncthreads();
    }
    const float mu  = rs_[0] * (1.f/DD);
    const float var = rq_[0] * (1.f/DD) - mu*mu;
    const float rstd = rsqrtf(var + eps);
    const float* ar = ada + (long)b * SIXD;
    #pragma unroll
    for (int i = 0; i < 4; ++i) {
        const int d = tid + 256*i;
        float y = (v[i] - mu) * rstd * w[d] + bias[d];
        if (MOD) y = y * (1.f + ar[scale_off + d]) + ar[shift_off + d];
        const long idx = (long)row * DD + d;
        if (OUT == 0) o32[idx] = y;
        else if (OUT == 1) { ushort h, l; split_bf(y, h, l); oh[idx] = h; ol[idx] = l; }
        else oh[idx] = f2bf(y);
    }
}

// Row softmax over 1024 -> split bf16 hi/lo
__global__ __launch_bounds__(256) void softmax_split(
    const float* __restrict__ in, ushort* __restrict__ oh, ushort* __restrict__ ol)
{
    const long row = blockIdx.x;
    const float* p = in + row * 1024;
    const int tid = threadIdx.x;
    float v[4]; float mx = -INFINITY;
    #pragma unroll
    for (int i = 0; i < 4; ++i) { v[i] = p[tid + 256*i]; mx = fmaxf(mx, v[i]); }
    __shared__ float red[256];
    red[tid] = mx; __syncthreads();
    for (int off = 128; off > 0; off >>= 1) {
        if (tid < off) red[tid] = fmaxf(red[tid], red[tid+off]);
        __syncthreads();
    }
    const float rowmax = red[0];
    __syncthreads();
    float s = 0.f;
    #pragma unroll
    for (int i = 0; i < 4; ++i) { v[i] = expf(v[i] - rowmax); s += v[i]; }
    red[tid] = s; __syncthreads();
    for (int off = 128; off > 0; off >>= 1) {
        if (tid < off) red[tid] += red[tid+off];
        __syncthreads();
    }
    const float inv = 1.f / red[0];
    #pragma unroll
    for (int i = 0; i < 4; ++i) {
        ushort h, l; split_bf(v[i] * inv, h, l);
        oh[row*1024 + tid + 256*i] = h;
        ol[row*1024 + tid + 256*i] = l;
    }
}

// Fused: h2 = modulate(ln(x2)) fp32, logits = h2 @ rw + rb (exact router)
__global__ __launch_bounds__(256) void router_fused(
    const float* __restrict__ x2, const float* __restrict__ fw, const float* __restrict__ fb,
    const float* __restrict__ ada, const float* __restrict__ rw, const float* __restrict__ rb,
    float* __restrict__ logits)
{
    const int row = blockIdx.x;
    const int b = row >> 10;
    const int tid = threadIdx.x;
    const float* xr = x2 + (long)row * DD;
    float v[4]; float s = 0.f, q = 0.f;
    #pragma unroll
    for (int i = 0; i < 4; ++i) { v[i] = xr[tid + 256*i]; s += v[i]; q += v[i]*v[i]; }
    __shared__ float rs_[256], rq_[256];
    rs_[tid] = s; rq_[tid] = q; __syncthreads();
    for (int off = 128; off > 0; off >>= 1) {
        if (tid < off) { rs_[tid] += rs_[tid+off]; rq_[tid] += rq_[tid+off]; }
        __syncthreads();
    }
    const float mu  = rs_[0] * (1.f/DD);
    const float var = rq_[0] * (1.f/DD) - mu*mu;
    const float rstd = rsqrtf(var + 1e-5f);
    const float* ar = ada + (long)b * SIXD;
    float acc[4] = {0.f, 0.f, 0.f, 0.f};
    #pragma unroll
    for (int i = 0; i < 4; ++i) {
        const int d = tid + 256*i;
        float h = (v[i] - mu) * rstd * fw[d] + fb[d];
        h = h * (1.f + ar[4096 + d]) + ar[3072 + d];
        const float* r4 = rw + (long)d * 4;
        acc[0] += h*r4[0]; acc[1] += h*r4[1]; acc[2] += h*r4[2]; acc[3] += h*r4[3];
    }
    __syncthreads();
    __shared__ float red[256];
    for (int e = 0; e < EE; ++e) {
        red[tid] = acc[e]; __syncthreads();
        for (int off = 128; off > 0; off >>= 1) {
            if (tid < off) red[tid] += red[tid+off];
            __syncthreads();
        }
        if (tid == 0) logits[(long)row * EE + e] = red[0] + rb[e];
        __syncthreads();
    }
}

__global__ __launch_bounds__(256) void router_norm_kernel(
    const float* __restrict__ logits, float* __restrict__ nrm)
{
    const int b = blockIdx.x >> 2, e = blockIdx.x & 3;
    const int tid = threadIdx.x;
    float s = 0.f;
    for (int si = tid; si < SS; si += 256) {
        const float v = logits[((long)b * SS + si) * EE + e];
        s += v * v;
    }
    __shared__ float red[256];
    red[tid] = s; __syncthreads();
    for (int off = 128; off > 0; off >>= 1) {
        if (tid < off) red[tid] += red[tid+off];
        __syncthreads();
    }
    if (tid == 0) nrm[blockIdx.x] = sqrtf(red[0]);
}

__global__ __launch_bounds__(256) void router_post_kernel(
    const float* __restrict__ logits, const float* __restrict__ nrm,
    float* __restrict__ probs, float* __restrict__ combine)
{
    const long row = (long)blockIdx.x * 256 + threadIdx.x;
    const int b = (int)(row >> 10);
    float l[4], p[4];
    #pragma unroll
    for (int e = 0; e < 4; ++e)
        l[e] = logits[row*4 + e] / fmaxf(nrm[b*4 + e], 1e-12f);
    const float mx = fmaxf(fmaxf(l[0], l[1]), fmaxf(l[2], l[3]));
    float s = 0.f;
    #pragma unroll
    for (int e = 0; e < 4; ++e) { p[e] = expf(l[e] - mx); s += p[e]; }
    const float inv = 1.f / s;
    #pragma unroll
    for (int e = 0; e < 4; ++e) { p[e] *= inv; probs[row*4 + e] = p[e]; }
    int i1 = 0;
    #pragma unroll
    for (int e = 1; e < 4; ++e) if (p[e] > p[i1]) i1 = e;
    int i2 = (i1 == 0) ? 1 : 0;
    #pragma unroll
    for (int e = 0; e < 4; ++e) if (e != i1 && p[e] > p[i2]) i2 = e;
    float c[4] = {0.f, 0.f, 0.f, 0.f};
    c[i1] = p[i1]; c[i2] = p[i2];
    #pragma unroll
    for (int e = 0; e < 4; ++e) combine[row*4 + e] = c[e];
}

__global__ __launch_bounds__(256) void aux_kernel(
    const float* __restrict__ probs, float* __restrict__ aux)
{
    const int tid = threadIdx.x;
    float acc = 0.f;
    for (int i = tid; i < SS*EE; i += 256) {
        const float avg = 0.25f * (probs[i] + probs[SS*EE + i] +
                                   probs[2*SS*EE + i] + probs[3*SS*EE + i]);
        const float d = 0.25f - avg;
        acc += d * d;
    }
    __shared__ float red[256];
    red[tid] = acc; __syncthreads();
    for (int off = 128; off > 0; off >>= 1) {
        if (tid < off) red[tid] += red[tid+off];
        __syncthreads();
    }
    if (tid == 0) aux[0] = red[0];
}

// Token->expert compaction: slot order nondeterministic (atomic), harmless —
// each (token,expert) row computed identically; output accumulated per token.
__global__ __launch_bounds__(1024) void compact_kernel(
    const float* __restrict__ comb, int* __restrict__ tokidx, int* __restrict__ cnt)
{
    __shared__ int lc[4];
    const int tid = threadIdx.x;
    if (tid < 4) lc[tid] = 0;
    for (int i = tid; i < TSLOT; i += 1024) tokidx[i] = -1;
    __syncthreads();
    for (int t = tid; t < BB*SS; t += 1024) {
        #pragma unroll
        for (int e = 0; e < 4; ++e) {
            if (comb[t*4 + e] > 0.f) {
                const int s = atomicAdd(&lc[e], 1);
                tokidx[e * ESLOT + s] = t;
            }
        }
    }
    __syncthreads();
    if (tid < 4) cnt[tid] = lc[tid];
}

__global__ __launch_bounds__(256) void zero_kernel(float4* __restrict__ out)
{
    out[(long)blockIdx.x * 256 + threadIdx.x] = float4{0.f, 0.f, 0.f, 0.f};
}

// ---------------------------------------------------------------------------
extern "C" void kernel_launch(void* const* d_in, const int* in_sizes, int n_in,
                              void* d_out, int out_size, void* d_ws, size_t ws_size,
                              hipStream_t stream)
{
    (void)in_sizes; (void)n_in; (void)out_size; (void)ws_size;
    const float* x     = (const float*)d_in[0];
    const float* adaln = (const float*)d_in[2];
    const float* wq    = (const float*)d_in[3];
    const float* wk    = (const float*)d_in[4];
    const float* wv    = (const float*)d_in[5];
    const float* wo    = (const float*)d_in[6];
    const float* qn_w  = (const float*)d_in[7];
    const float* qn_b  = (const float*)d_in[8];
    const float* kn_w  = (const float*)d_in[9];
    const float* kn_b  = (const float*)d_in[10];
    const float* an_w  = (const float*)d_in[11];
    const float* an_b  = (const float*)d_in[12];
    const float* fn_w  = (const float*)d_in[13];
    const float* fn_b  = (const float*)d_in[14];
    const float* w1    = (const float*)d_in[15];
    const float* w2    = (const float*)d_in[16];
    const float* w3    = (const float*)d_in[17];
    const float* rw    = (const float*)d_in[18];
    const float* rb    = (const float*)d_in[19];
    const float* aw    = (const float*)d_in[20];
    const float* ab    = (const float*)d_in[21];
    float* out = (float*)d_out;

    const long NBAT = (long)SS * DD;          // 1048576
    const long NBUF = (long)BB * SS * DD;     // 4194304
#define MB(x) ((long)(x) * 1048576L)

    char* P = (char*)d_ws;
    float* ada    = (float*)P;                       // 24576 f
    float* logits = (float*)(P + 98304);             // 16384 f
    float* probs  = logits + 16384;
    float* comb   = probs  + 16384;
    float* nrm    = comb   + 16384;                  // 16 f
    int*   cnt    = (int*)(nrm + 16);                // 4
    int*   tokidx = cnt + 4;                         // 16896

    char* A0 = P + MB(1);
    // [0,12): wqT/wkT/wvT split -> woT [0,4) -> w1Tc [0,11.5)
    ushort* wqT_h = (ushort*)(A0 + MB(0));  ushort* wqT_l = (ushort*)(A0 + MB(2));
    ushort* wkT_h = (ushort*)(A0 + MB(4));  ushort* wkT_l = (ushort*)(A0 + MB(6));
    ushort* wvT_h = (ushort*)(A0 + MB(8));  ushort* wvT_l = (ushort*)(A0 + MB(10));
    ushort* woT_h = (ushort*)(A0 + MB(0));  ushort* woT_l = (ushort*)(A0 + MB(2));
    ushort* w1Tc  = (ushort*)(A0 + MB(0));           // [E][1408][1024] bf16
    // [12,28): h split -> sc -> ao split -> actb(part)
    ushort* h_h  = (ushort*)(A0 + MB(12));  ushort* h_l  = (ushort*)(A0 + MB(20));
    float*  sc   = (float*) (A0 + MB(12));
    ushort* ao_h = (ushort*)(A0 + MB(12));  ushort* ao_l = (ushort*)(A0 + MB(20));
    ushort* actb = (ushort*)(A0 + MB(12));           // [16896][1408] bf16, 45.4 MiB
    // [28,44): q32/k32 (sequenced) -> at split -> actb(part)
    float*  qk32 = (float*) (A0 + MB(28));
    ushort* at_h = (ushort*)(A0 + MB(28));  ushort* at_l = (ushort*)(A0 + MB(36));
    // [44,60): v split -> actb(part)
    ushort* v_h  = (ushort*)(A0 + MB(44));  ushort* v_l  = (ushort*)(A0 + MB(52));
    // [60,76): qT split -> x2 -> w3Tc [60,71.5)
    ushort* qT_h = (ushort*)(A0 + MB(60));  ushort* qT_l = (ushort*)(A0 + MB(68));
    float*  x2   = (float*) (A0 + MB(60));
    ushort* w3Tc = (ushort*)(A0 + MB(60));
    // [76,92): kT split -> h2bf [76,84); w2Tc [84,95.5)
    ushort* kT_h = (ushort*)(A0 + MB(76));  ushort* kT_l = (ushort*)(A0 + MB(84));
    ushort* h2bf = (ushort*)(A0 + MB(76));
    ushort* w2Tc = (ushort*)(A0 + MB(84));           // [E][1024][1408] bf16

    const dim3 blk(256);

    // 1. adaLN vector
    ada_kernel<<<dim3(SIXD/256, BB), blk, 0, stream>>>(adaln, aw, ab, ada);

    // 2. attention weight transposes (split)
    transp<true><<<dim3(16,16,1), blk, 0, stream>>>(wq, wqT_h, wqT_l, 1024, 1024, 0, 0);
    transp<true><<<dim3(16,16,1), blk, 0, stream>>>(wk, wkT_h, wkT_l, 1024, 1024, 0, 0);
    transp<true><<<dim3(16,16,1), blk, 0, stream>>>(wv, wvT_h, wvT_l, 1024, 1024, 0, 0);

    // 3. h = modulate(ln(x)) -> split bf16
    ln_kernel<1,true><<<4096, blk, 0, stream>>>(x, an_w, an_b, ada, 1024, 0,
                                                nullptr, h_h, h_l, 1e-5f);

    // 4. q: project, LN, transpose-split   (qk32 reused for k afterwards)
    mgemm<0,true,false,false,false><<<dim3(8,32,1), blk, 0, stream>>>(
        h_h, h_l, wqT_h, wqT_l, qk32, nullptr, nullptr, nullptr, nullptr, nullptr,
        1024, 1024, 1024, 1024, 0, 0, 0);
    ln_kernel<0,false><<<4096, blk, 0, stream>>>(qk32, qn_w, qn_b, ada, 0, 0, qk32, nullptr, nullptr, 1e-5f);
    transp<true><<<dim3(16,16,BB), blk, 0, stream>>>(qk32, qT_h, qT_l, 1024, 1024, NBAT, NBAT);

    // 5. k: project, LN, transpose-split
    mgemm<0,true,false,false,false><<<dim3(8,32,1), blk, 0, stream>>>(
        h_h, h_l, wkT_h, wkT_l, qk32, nullptr, nullptr, nullptr, nullptr, nullptr,
        1024, 1024, 1024, 1024, 0, 0, 0);
    ln_kernel<0,false><<<4096, blk, 0, stream>>>(qk32, kn_w, kn_b, ada, 0, 0, qk32, nullptr, nullptr, 1e-5f);
    transp<true><<<dim3(16,16,BB), blk, 0, stream>>>(qk32, kT_h, kT_l, 1024, 1024, NBAT, NBAT);

    // 6. v: project -> split store
    mgemm<5,true,false,false,false><<<dim3(8,32,1), blk, 0, stream>>>(
        h_h, h_l, wvT_h, wvT_l, v_h, v_l, nullptr, nullptr, nullptr, nullptr,
        1024, 1024, 1024, 1024, 0, 0, 0);

    // 7. wo transpose (into reclaimed wqT region)
    transp<true><<<dim3(16,16,1), blk, 0, stream>>>(wo, woT_h, woT_l, 1024, 1024, 0, 0);

    // 8. scores[b,d,e] = sum_s qT[b,d,s]*kT[b,e,s]
    mgemm<0,true,false,false,false><<<dim3(8,8,BB), blk, 0, stream>>>(
        qT_h, qT_l, kT_h, kT_l, sc, nullptr, nullptr, nullptr, nullptr, nullptr,
        1024, 1024, 1024, 1024, NBAT, NBAT, NBAT);

    // 9. softmax -> attn split
    softmax_split<<<4096, blk, 0, stream>>>(sc, at_h, at_l);

    // 10. ao[b,s,d] = sum_e v[b,s,e]*attn[b,d,e] -> split store
    mgemm<5,true,false,false,false><<<dim3(8,8,BB), blk, 0, stream>>>(
        v_h, v_l, at_h, at_l, ao_h, ao_l, nullptr, nullptr, nullptr, nullptr,
        1024, 1024, 1024, 1024, NBAT, NBAT, NBAT);

    // 11. x2 = x + gate_msa * (ao @ wo)
    mgemm<2,true,false,false,false><<<dim3(8,32,1), blk, 0, stream>>>(
        ao_h, ao_l, woT_h, woT_l, x2, nullptr, x, ada, nullptr, nullptr,
        1024, 1024, 1024, 1024, 0, 0, 0);

    // 12. h2 = modulate(ln(x2)) -> bf16 (MoE input)
    ln_kernel<2,true><<<4096, blk, 0, stream>>>(x2, fn_w, fn_b, ada, 4096, 3072,
                                                nullptr, h2bf, nullptr, 1e-5f);

    // 13. router (exact fp32), compaction, zero out
    router_fused<<<4096, blk, 0, stream>>>(x2, fn_w, fn_b, ada, rw, rb, logits);
    router_norm_kernel<<<BB*EE, blk, 0, stream>>>(logits, nrm);
    router_post_kernel<<<16, blk, 0, stream>>>(logits, nrm, probs, comb);
    aux_kernel<<<1, blk, 0, stream>>>(probs, out + NBUF);
    compact_kernel<<<1, dim3(1024), 0, stream>>>(comb, tokidx, cnt);
    zero_kernel<<<dim3(4096), blk, 0, stream>>>((float4*)out);

    // 14. MoE: top-2 sparse, HID chunked by 1408
    for (int c = 0; c < HID/HC; ++c) {
        transp<false><<<dim3(22,16,4), blk, 0, stream>>>(
            w1 + (long)c*HC, w1Tc, nullptr, HID, 1024, (long)DD*HID, (long)HC*1024);
        transp<false><<<dim3(22,16,4), blk, 0, stream>>>(
            w3 + (long)c*HC, w3Tc, nullptr, HID, 1024, (long)DD*HID, (long)HC*1024);
        transp<false><<<dim3(16,22,4), blk, 0, stream>>>(
            w2 + (long)c*HC*DD, w2Tc, nullptr, DD, HC, (long)HID*DD, (long)DD*HC);
        // act[slot] = bf16( sin(h2@w1c) * (h2@w3c) )   (gathered rows, dual-B)
        mgemm<6,false,true,true,true><<<dim3(11,132,1), blk, 0, stream>>>(
            h2bf, nullptr, w1Tc, w3Tc, actb, nullptr, nullptr, nullptr, tokidx, cnt,
            1024, 1024, 1024, HC, 0, (long)HC*1024, 0);
        // out[token] += comb[token,e] * (act @ w2c)  (atomic scatter)
        mgemm<7,false,false,true,false><<<dim3(8,132,1), blk, 0, stream>>>(
            actb, nullptr, w2Tc, nullptr, out, nullptr, comb, nullptr, tokidx, cnt,
            HC, HC, HC, 1024, 0, (long)DD*HC, 0);
    }
#undef MB
}

// Round 4
// 846.494 us; speedup vs baseline: 8.2412x; 1.2003x over previous
//
#include <hip/hip_runtime.h>
#include <hip/hip_bf16.h>
#include <math.h>

// Problem constants
#define BB 4
#define SS 1024
#define DD 1024
#define EE 4
#define HID 2816
#define HC 1408         // HID chunk (2816 = 2*1408)
#define SIXD 6144
#define NSLOT 8704      // packed slot space (8192 + per-expert 128-padding)
#define NMB 68          // max m-blocks of 128 over packed slots

typedef __bf16 v8bf __attribute__((ext_vector_type(8)));
typedef float  v4f  __attribute__((ext_vector_type(4)));

__device__ __forceinline__ ushort f2bf(float f) {
    union { float f; unsigned u; } v; v.f = f;
    unsigned r = v.u + 0x7fff + ((v.u >> 16) & 1);   // RNE
    return (ushort)(r >> 16);
}
__device__ __forceinline__ float bf2f(ushort u) {
    union { unsigned u; float f; } v; v.u = ((unsigned)u) << 16;
    return v.f;
}
__device__ __forceinline__ void split_bf(float x, ushort& h, ushort& l) {
    h = f2bf(x);
    l = f2bf(x - bf2f(h));
}
__device__ __forceinline__ void gload16(const void* g, void* l) {
    __builtin_amdgcn_global_load_lds((const __attribute__((address_space(1))) void*)g,
                                     (__attribute__((address_space(3))) void*)l, 16, 0, 0);
}
// wait until at most N vector-memory ops outstanding; lgkm/exp untouched
template<int N> __device__ __forceinline__ void wait_vm() {
    __builtin_amdgcn_s_waitcnt((N & 15) | (0x7 << 4) | (0xF << 8) | ((N >> 4) << 14));
}

// ---------------------------------------------------------------------------
// MFMA GEMM, 128(M)x64(N) tile, BK=32, 256 threads = 4 waves (each 32x64),
// double-buffered LDS, manual s_barrier + vmcnt(L) 1-deep pipeline.
// C[M][N] = A[M][K] * B^T (B stored [N][K]), bf16 operands.
// SPLIT: hi+lo pairs, 3 MFMA passes. MOE: m-block map (mbe/mbm) in slot space.
// EPI: 0 fp32 store | 2 resgate x+gate*val | 5 split bf16 store |
//      7 atomic scatter out[tok] += comb*val
// ---------------------------------------------------------------------------
template<int EPI, bool SPLIT, bool MOE>
__global__ __launch_bounds__(256, 2) void mgemm(
    const ushort* __restrict__ Ah, const ushort* __restrict__ Al,
    const ushort* __restrict__ Bh, const ushort* __restrict__ Bl,
    void* __restrict__ Cv, ushort* __restrict__ C2,
    const float* __restrict__ f1, const float* __restrict__ f2,
    const int* __restrict__ tokidx, const int* __restrict__ mbe,
    const int* __restrict__ mbm,
    int K, int lda, int ldb, int ldc,
    long sA, long sB, long sC)
{
    constexpr int STG = SPLIT ? 12288 : 6144;        // ushorts per stage
    constexpr int BH  = SPLIT ? 8192 : 4096;         // B-hi offset in stage
    constexpr int L   = SPLIT ? 6 : 3;               // loads/thread/tile
    __shared__ __align__(16) ushort smem[2 * STG];

    const int tid  = threadIdx.x;
    const int wv   = tid >> 6, lane = tid & 63;
    const int n0 = blockIdx.x * 64;

    int eexp = 0, m0;
    if (MOE) {
        eexp = mbe[blockIdx.y];
        if (eexp < 0) return;
        m0 = mbm[blockIdx.y];
    } else {
        m0 = blockIdx.y * 128;
    }
    const long zA = MOE ? 0 : (long)blockIdx.z * sA;
    const long zB = MOE ? (long)eexp * sB : (long)blockIdx.z * sB;
    const long zC = MOE ? 0 : (long)blockIdx.z * sC;

    const int lrow = tid >> 2;           // 0..63 (4 lanes per row)
    const int skq  = (tid & 3) * 8;      // 16B each
    const int lm   = lane & 15;
    const int q8   = (lane >> 4) * 8;

    v4f acc[2][4];
    const v4f vzero = {0.f, 0.f, 0.f, 0.f};
    #pragma unroll
    for (int i = 0; i < 2; ++i)
        #pragma unroll
        for (int j = 0; j < 4; ++j) acc[i][j] = vzero;

    auto issue = [&](int kt, int st) {
        const long kk = (long)kt * 32 + skq;
        ushort* base = smem + st * STG;
        #pragma unroll
        for (int c = 0; c < 2; ++c) {
            const int row  = c * 64 + lrow;
            const int loff = (c * 64 + wv * 16) * 32;
            gload16(Ah + zA + (long)(m0 + row) * lda + kk, base + loff);
            if (SPLIT)
                gload16(Al + zA + (long)(m0 + row) * lda + kk, base + 4096 + loff);
        }
        {
            const int loff = wv * 16 * 32;
            gload16(Bh + zB + (long)(n0 + lrow) * ldb + kk, base + BH + loff);
            if (SPLIT)
                gload16(Bl + zB + (long)(n0 + lrow) * ldb + kk, base + BH + 2048 + loff);
        }
    };

    const int nk = K / 32;
    issue(0, 0);
    for (int kt = 0; kt < nk; ++kt) {
        const int st = kt & 1;
        if (kt) __builtin_amdgcn_s_barrier();
        const bool hasNext = (kt + 1 < nk);
        if (hasNext) issue(kt + 1, st ^ 1);
        if (hasNext) wait_vm<L>(); else wait_vm<0>();
        __builtin_amdgcn_s_barrier();
        const ushort* As = smem + st * STG;
        v8bf a[2], b[4];
        #pragma unroll
        for (int i = 0; i < 2; ++i) a[i] = *(const v8bf*)(As + (wv*32 + 16*i + lm) * 32 + q8);
        #pragma unroll
        for (int j = 0; j < 4; ++j) b[j] = *(const v8bf*)(As + BH + (16*j + lm) * 32 + q8);
        #pragma unroll
        for (int i = 0; i < 2; ++i)
            #pragma unroll
            for (int j = 0; j < 4; ++j)
                acc[i][j] = __builtin_amdgcn_mfma_f32_16x16x32_bf16(a[i], b[j], acc[i][j], 0, 0, 0);
        if (SPLIT) {
            v8bf al[2], bl[4];
            #pragma unroll
            for (int i = 0; i < 2; ++i) al[i] = *(const v8bf*)(As + 4096 + (wv*32 + 16*i + lm) * 32 + q8);
            #pragma unroll
            for (int j = 0; j < 4; ++j) bl[j] = *(const v8bf*)(As + BH + 2048 + (16*j + lm) * 32 + q8);
            #pragma unroll
            for (int i = 0; i < 2; ++i)
                #pragma unroll
                for (int j = 0; j < 4; ++j) {
                    acc[i][j] = __builtin_amdgcn_mfma_f32_16x16x32_bf16(a[i],  bl[j], acc[i][j], 0, 0, 0);
                    acc[i][j] = __builtin_amdgcn_mfma_f32_16x16x32_bf16(al[i], b[j],  acc[i][j], 0, 0, 0);
                }
        }
    }

    const int r0 = (lane >> 4) * 4;
    if (EPI == 7) {
        #pragma unroll
        for (int i = 0; i < 2; ++i)
            #pragma unroll
            for (int r = 0; r < 4; ++r) {
                const int rowg = m0 + wv*32 + 16*i + r0 + r;
                const int t = tokidx[rowg];
                if (t >= 0) {
                    const float cw = f1[t * 4 + eexp];
                    #pragma unroll
                    for (int j = 0; j < 4; ++j)
                        atomicAdd((float*)Cv + (long)t * 1024 + n0 + 16*j + lm, cw * acc[i][j][r]);
                }
            }
    } else {
        #pragma unroll
        for (int i = 0; i < 2; ++i) {
            #pragma unroll
            for (int j = 0; j < 4; ++j) {
                const int colg = n0 + 16*j + lm;
                #pragma unroll
                for (int r = 0; r < 4; ++r) {
                    const long rowg = (long)(m0 + wv*32 + 16*i + r0 + r);
                    const long idx  = zC + rowg * ldc + colg;
                    const float val = acc[i][j][r];
                    if (EPI == 0) {
                        ((float*)Cv)[idx] = val;
                    } else if (EPI == 2) {
                        ((float*)Cv)[idx] = f1[idx] + f2[(rowg >> 10) * SIXD + 2048 + colg] * val;
                    } else if (EPI == 5) {
                        ushort h, l; split_bf(val, h, l);
                        ((ushort*)Cv)[idx] = h;
                        C2[idx] = l;
                    }
                }
            }
        }
    }
}

// ---------------------------------------------------------------------------
// MoE h1h3 fused GEMM: 128(M)x64(N) tile, dual B (w1,w3), gathered A rows,
// epilogue actb = bf16(sin(acc1)*acc2). K=1024, lda=1024, ldb=1024, ldc=HC.
// ---------------------------------------------------------------------------
__global__ __launch_bounds__(256, 2) void mgemm_h1h3(
    const ushort* __restrict__ Ah, const ushort* __restrict__ B1,
    const ushort* __restrict__ B2, ushort* __restrict__ Cb,
    const int* __restrict__ tokidx, const int* __restrict__ mbe,
    const int* __restrict__ mbm, long sB)
{
    constexpr int STG = 8192;            // A 4096 + B1 2048 + B2 2048 ushorts
    __shared__ __align__(16) ushort smem[2 * STG];

    const int tid  = threadIdx.x;
    const int wv   = tid >> 6, lane = tid & 63;
    const int n0 = blockIdx.x * 64;
    const int eexp = mbe[blockIdx.y];
    if (eexp < 0) return;
    const int m0 = mbm[blockIdx.y];
    const long zB = (long)eexp * sB;

    const int lrow = tid >> 2;
    const int skq  = (tid & 3) * 8;
    const int lm   = lane & 15;
    const int q8   = (lane >> 4) * 8;

    long arow[2];
    #pragma unroll
    for (int c = 0; c < 2; ++c) {
        const int t = tokidx[m0 + c * 64 + lrow];
        arow[c] = (t < 0) ? 0 : (long)t;
    }

    v4f acc[2][4], acc2[2][4];
    const v4f vzero = {0.f, 0.f, 0.f, 0.f};
    #pragma unroll
    for (int i = 0; i < 2; ++i)
        #pragma unroll
        for (int j = 0; j < 4; ++j) { acc[i][j] = vzero; acc2[i][j] = vzero; }

    auto issue = [&](int kt, int st) {
        const long kk = (long)kt * 32 + skq;
        ushort* base = smem + st * STG;
        #pragma unroll
        for (int c = 0; c < 2; ++c)
            gload16(Ah + arow[c] * 1024 + kk, base + (c * 64 + wv * 16) * 32);
        const int loff = wv * 16 * 32;
        gload16(B1 + zB + (long)(n0 + lrow) * 1024 + kk, base + 4096 + loff);
        gload16(B2 + zB + (long)(n0 + lrow) * 1024 + kk, base + 6144 + loff);
    };

    issue(0, 0);
    for (int kt = 0; kt < 32; ++kt) {
        const int st = kt & 1;
        if (kt) __builtin_amdgcn_s_barrier();
        const bool hasNext = (kt + 1 < 32);
        if (hasNext) issue(kt + 1, st ^ 1);
        if (hasNext) wait_vm<4>(); else wait_vm<0>();
        __builtin_amdgcn_s_barrier();
        const ushort* As = smem + st * STG;
        v8bf a[2], b1[4], b2[4];
        #pragma unroll
        for (int i = 0; i < 2; ++i) a[i] = *(const v8bf*)(As + (wv*32 + 16*i + lm) * 32 + q8);
        #pragma unroll
        for (int j = 0; j < 4; ++j) {
            b1[j] = *(const v8bf*)(As + 4096 + (16*j + lm) * 32 + q8);
            b2[j] = *(const v8bf*)(As + 6144 + (16*j + lm) * 32 + q8);
        }
        #pragma unroll
        for (int i = 0; i < 2; ++i)
            #pragma unroll
            for (int j = 0; j < 4; ++j) {
                acc[i][j]  = __builtin_amdgcn_mfma_f32_16x16x32_bf16(a[i], b1[j], acc[i][j],  0, 0, 0);
                acc2[i][j] = __builtin_amdgcn_mfma_f32_16x16x32_bf16(a[i], b2[j], acc2[i][j], 0, 0, 0);
            }
    }

    const int r0 = (lane >> 4) * 4;
    #pragma unroll
    for (int i = 0; i < 2; ++i)
        #pragma unroll
        for (int j = 0; j < 4; ++j) {
            const int colg = n0 + 16*j + lm;
            #pragma unroll
            for (int r = 0; r < 4; ++r) {
                const long rowg = (long)(m0 + wv*32 + 16*i + r0 + r);
                Cb[rowg * HC + colg] = f2bf(sinf(acc[i][j][r]) * acc2[i][j][r]);
            }
        }
}

// ---------------------------------------------------------------------------
// Transpose fp32 [K][N] -> bf16 [N][K], optional hi/lo split.
// ---------------------------------------------------------------------------
template<bool SP>
__global__ __launch_bounds__(256) void transp(
    const float* __restrict__ in, ushort* __restrict__ oh, ushort* __restrict__ ol,
    int ldin, int ldout, long sIn, long sOut)
{
    __shared__ float T[64][65];
    const int n0 = blockIdx.x * 64, k0 = blockIdx.y * 64;
    in += (long)blockIdx.z * sIn;
    oh += (long)blockIdx.z * sOut;
    if (SP) ol += (long)blockIdx.z * sOut;
    const int t = threadIdx.x;
    const int rr = t >> 4, c4 = (t & 15) * 4;
    #pragma unroll
    for (int p = 0; p < 4; ++p) {
        const int r = rr + p * 16;
        const float4 v = *(const float4*)(in + (long)(k0 + r) * ldin + n0 + c4);
        T[c4+0][r] = v.x; T[c4+1][r] = v.y; T[c4+2][r] = v.z; T[c4+3][r] = v.w;
    }
    __syncthreads();
    #pragma unroll
    for (int p = 0; p < 4; ++p) {
        const int idx = t + 256 * p;
        const int n = idx >> 4, c = (idx & 15) * 4;
        ushort4 wh, wl;
        float x0 = T[n][c], x1 = T[n][c+1], x2 = T[n][c+2], x3 = T[n][c+3];
        if (SP) {
            split_bf(x0, wh.x, wl.x); split_bf(x1, wh.y, wl.y);
            split_bf(x2, wh.z, wl.z); split_bf(x3, wh.w, wl.w);
        } else {
            wh.x = f2bf(x0); wh.y = f2bf(x1); wh.z = f2bf(x2); wh.w = f2bf(x3);
        }
        *(ushort4*)(oh + (long)(n0 + n) * ldout + k0 + c) = wh;
        if (SP) *(ushort4*)(ol + (long)(n0 + n) * ldout + k0 + c) = wl;
    }
}

// ---------------------------------------------------------------------------
__global__ __launch_bounds__(256) void ada_kernel(
    const float* __restrict__ adaln, const float* __restrict__ aw,
    const float* __restrict__ ab, float* __restrict__ ada)
{
    __shared__ float s[DD];
    const int b = blockIdx.y;
    const int tid = threadIdx.x;
    for (int i = tid; i < DD; i += 256) {
        const float v = adaln[(long)b * DD + i];
        s[i] = v / (1.f + expf(-v));
    }
    __syncthreads();
    const int n = blockIdx.x * 256 + tid;
    float acc = 0.f;
    for (int k = 0; k < DD; ++k) acc += s[k] * aw[(long)k * SIXD + n];
    ada[(long)b * SIXD + n] = acc + ab[n];
}

// LayerNorm over D=1024; OUT: 0 fp32, 1 split bf16 hi/lo, 2 bf16
template<int OUT, bool MOD>
__global__ __launch_bounds__(256) void ln_kernel(
    const float* __restrict__ x, const float* __restrict__ w, const float* __restrict__ bias,
    const float* __restrict__ ada, int scale_off, int shift_off,
    float* __restrict__ o32, ushort* __restrict__ oh, ushort* __restrict__ ol, float eps)
{
    const int row = blockIdx.x;
    const int b = row >> 10;
    const int tid = threadIdx.x;
    const float* xr = x + (long)row * DD;
    float v[4]; float s = 0.f, q = 0.f;
    #pragma unroll
    for (int i = 0; i < 4; ++i) { v[i] = xr[tid + 256*i]; s += v[i]; q += v[i]*v[i]; }
    __shared__ float rs_[256], rq_[256];
    rs_[tid] = s; rq_[tid] = q; __syncthreads();
    for (int off = 128; off > 0; off >>= 1) {
        if (tid < off) { rs_[tid] += rs_[tid+off]; rq_[tid] += rq_[tid+off]; }
        __syncthreads();
    }
    const float mu  = rs_[0] * (1.f/DD);
    const float var = rq_[0] * (1.f/DD) - mu*mu;
    const float rstd = rsqrtf(var + eps);
    const float* ar = ada + (long)b * SIXD;
    #pragma unroll
    for (int i = 0; i < 4; ++i) {
        const int d = tid + 256*i;
        float y = (v[i] - mu) * rstd * w[d] + bias[d];
        if (MOD) y = y * (1.f + ar[scale_off + d]) + ar[shift_off + d];
        const long idx = (long)row * DD + d;
        if (OUT == 0) o32[idx] = y;
        else if (OUT == 1) { ushort h, l; split_bf(y, h, l); oh[idx] = h; ol[idx] = l; }
        else oh[idx] = f2bf(y);
    }
}

// Row softmax over 1024 -> split bf16 hi/lo
__global__ __launch_bounds__(256) void softmax_split(
    const float* __restrict__ in, ushort* __restrict__ oh, ushort* __restrict__ ol)
{
    const long row = blockIdx.x;
    const float* p = in + row * 1024;
    const int tid = threadIdx.x;
    float v[4]; float mx = -INFINITY;
    #pragma unroll
    for (int i = 0; i < 4; ++i) { v[i] = p[tid + 256*i]; mx = fmaxf(mx, v[i]); }
    __shared__ float red[256];
    red[tid] = mx; __syncthreads();
    for (int off = 128; off > 0; off >>= 1) {
        if (tid < off) red[tid] = fmaxf(red[tid], red[tid+off]);
        __syncthreads();
    }
    const float rowmax = red[0];
    __syncthreads();
    float s = 0.f;
    #pragma unroll
    for (int i = 0; i < 4; ++i) { v[i] = expf(v[i] - rowmax); s += v[i]; }
    red[tid] = s; __syncthreads();
    for (int off = 128; off > 0; off >>= 1) {
        if (tid < off) red[tid] += red[tid+off];
        __syncthreads();
    }
    const float inv = 1.f / red[0];
    #pragma unroll
    for (int i = 0; i < 4; ++i) {
        ushort h, l; split_bf(v[i] * inv, h, l);
        oh[row*1024 + tid + 256*i] = h;
        ol[row*1024 + tid + 256*i] = l;
    }
}

// Fused: h2 = modulate(ln(x2)) fp32, logits = h2 @ rw + rb (exact router)
__global__ __launch_bounds__(256) void router_fused(
    const float* __restrict__ x2, const float* __restrict__ fw, const float* __restrict__ fb,
    const float* __restrict__ ada, const float* __restrict__ rw, const float* __restrict__ rb,
    float* __restrict__ logits)
{
    const int row = blockIdx.x;
    const int b = row >> 10;
    const int tid = threadIdx.x;
    const float* xr = x2 + (long)row * DD;
    float v[4]; float s = 0.f, q = 0.f;
    #pragma unroll
    for (int i = 0; i < 4; ++i) { v[i] = xr[tid + 256*i]; s += v[i]; q += v[i]*v[i]; }
    __shared__ float rs_[256], rq_[256];
    rs_[tid] = s; rq_[tid] = q; __syncthreads();
    for (int off = 128; off > 0; off >>= 1) {
        if (tid < off) { rs_[tid] += rs_[tid+off]; rq_[tid] += rq_[tid+off]; }
        __syncthreads();
    }
    const float mu  = rs_[0] * (1.f/DD);
    const float var = rq_[0] * (1.f/DD) - mu*mu;
    const float rstd = rsqrtf(var + 1e-5f);
    const float* ar = ada + (long)b * SIXD;
    float acc[4] = {0.f, 0.f, 0.f, 0.f};
    #pragma unroll
    for (int i = 0; i < 4; ++i) {
        const int d = tid + 256*i;
        float h = (v[i] - mu) * rstd * fw[d] + fb[d];
        h = h * (1.f + ar[4096 + d]) + ar[3072 + d];
        const float* r4 = rw + (long)d * 4;
        acc[0] += h*r4[0]; acc[1] += h*r4[1]; acc[2] += h*r4[2]; acc[3] += h*r4[3];
    }
    __syncthreads();
    __shared__ float red[256];
    for (int e = 0; e < EE; ++e) {
        red[tid] = acc[e]; __syncthreads();
        for (int off = 128; off > 0; off >>= 1) {
            if (tid < off) red[tid] += red[tid+off];
            __syncthreads();
        }
        if (tid == 0) logits[(long)row * EE + e] = red[0] + rb[e];
        __syncthreads();
    }
}

// ---------------------------------------------------------------------------
// Merged router post-processing (single block, 1024 threads):
// seq-dim L2 norms, softmax, top-2 combine, aux loss, packed compaction
// with 128-aligned per-expert offsets and m-block map.
// Slot order within an expert is nondeterministic (atomics) — harmless.
// ---------------------------------------------------------------------------
__global__ __launch_bounds__(1024) void router_all(
    const float* __restrict__ logits, float* __restrict__ comb,
    float* __restrict__ auxout, int* __restrict__ tokidx,
    int* __restrict__ mbe, int* __restrict__ mbm)
{
    __shared__ float pl[16384];
    __shared__ float red[1024];
    __shared__ float nrm_l[16];
    __shared__ int lc[4], loff[4], lpos[4];
    const int tid = threadIdx.x;
    const int wv = tid >> 6, ln = tid & 63;
    // 1. L2 norms over seq dim: wave wv handles (b,e) = (wv>>2, wv&3)
    {
        const int b = wv >> 2, e = wv & 3;
        float s = 0.f;
        for (int it = 0; it < 16; ++it) {
            const float v = logits[(((long)b << 10) + ln + (it << 6)) * 4 + e];
            s += v * v;
        }
        for (int off = 32; off > 0; off >>= 1) s += __shfl_down(s, off, 64);
        if (ln == 0) nrm_l[wv] = fmaxf(sqrtf(s), 1e-12f);
    }
    if (tid < 4) lc[tid] = 0;
    __syncthreads();
    // 2. softmax + top-2 per row (4 rows/thread) + counts
    float cloc[4][4];
    const int rbase = tid * 4;
    for (int rr = 0; rr < 4; ++rr) {
        const int row = rbase + rr;
        const int b = row >> 10;
        float l[4], p[4];
        #pragma unroll
        for (int e = 0; e < 4; ++e) l[e] = logits[(long)row*4 + e] / nrm_l[b*4 + e];
        const float mx = fmaxf(fmaxf(l[0], l[1]), fmaxf(l[2], l[3]));
        float s = 0.f;
        #pragma unroll
        for (int e = 0; e < 4; ++e) { p[e] = expf(l[e] - mx); s += p[e]; }
        const float inv = 1.f / s;
        #pragma unroll
        for (int e = 0; e < 4; ++e) { p[e] *= inv; pl[row*4 + e] = p[e]; }
        int i1 = 0;
        #pragma unroll
        for (int e = 1; e < 4; ++e) if (p[e] > p[i1]) i1 = e;
        int i2 = (i1 == 0) ? 1 : 0;
        #pragma unroll
        for (int e = 0; e < 4; ++e) if (e != i1 && p[e] > p[i2]) i2 = e;
        #pragma unroll
        for (int e = 0; e < 4; ++e) {
            const float c = (e == i1) ? p[i1] : ((e == i2) ? p[i2] : 0.f);
            cloc[rr][e] = c;
            comb[(long)row*4 + e] = c;
            if (c > 0.f) atomicAdd(&lc[e], 1);
        }
    }
    __syncthreads();
    // 3. aux = sum_{s,e} (1/4 - mean_b p)^2
    float acc = 0.f;
    for (int i = tid; i < 4096; i += 1024) {
        const int s = i >> 2, e = i & 3;
        const float avg = 0.25f * (pl[s*4+e] + pl[(1024+s)*4+e] +
                                   pl[(2048+s)*4+e] + pl[(3072+s)*4+e]);
        const float d = 0.25f - avg;
        acc += d * d;
    }
    red[tid] = acc; __syncthreads();
    for (int off = 512; off > 0; off >>= 1) {
        if (tid < off) red[tid] += red[tid+off];
        __syncthreads();
    }
    if (tid == 0) auxout[0] = red[0];
    // 4. 128-aligned offsets + m-block map
    if (tid == 0) {
        int off0 = 0, nb = 0;
        for (int e = 0; e < 4; ++e) {
            loff[e] = off0; lpos[e] = 0;
            const int mb = (lc[e] + 127) >> 7;
            for (int k = 0; k < mb; ++k) { mbe[nb] = e; mbm[nb] = off0 + k*128; ++nb; }
            off0 += mb << 7;
        }
        for (; nb < NMB; ++nb) { mbe[nb] = -1; mbm[nb] = 0; }
    }
    for (int i = tid; i < NSLOT; i += 1024) tokidx[i] = -1;
    __syncthreads();
    // 5. fill slots
    for (int rr = 0; rr < 4; ++rr) {
        const int row = rbase + rr;
        #pragma unroll
        for (int e = 0; e < 4; ++e)
            if (cloc[rr][e] > 0.f) {
                const int s = atomicAdd(&lpos[e], 1);
                tokidx[loff[e] + s] = row;
            }
    }
}

__global__ __launch_bounds__(256) void zero_kernel(float4* __restrict__ out)
{
    out[(long)blockIdx.x * 256 + threadIdx.x] = float4{0.f, 0.f, 0.f, 0.f};
}

// ---------------------------------------------------------------------------
extern "C" void kernel_launch(void* const* d_in, const int* in_sizes, int n_in,
                              void* d_out, int out_size, void* d_ws, size_t ws_size,
                              hipStream_t stream)
{
    (void)in_sizes; (void)n_in; (void)out_size; (void)ws_size;
    const float* x     = (const float*)d_in[0];
    const float* adaln = (const float*)d_in[2];
    const float* wq    = (const float*)d_in[3];
    const float* wk    = (const float*)d_in[4];
    const float* wv    = (const float*)d_in[5];
    const float* wo    = (const float*)d_in[6];
    const float* qn_w  = (const float*)d_in[7];
    const float* qn_b  = (const float*)d_in[8];
    const float* kn_w  = (const float*)d_in[9];
    const float* kn_b  = (const float*)d_in[10];
    const float* an_w  = (const float*)d_in[11];
    const float* an_b  = (const float*)d_in[12];
    const float* fn_w  = (const float*)d_in[13];
    const float* fn_b  = (const float*)d_in[14];
    const float* w1    = (const float*)d_in[15];
    const float* w2    = (const float*)d_in[16];
    const float* w3    = (const float*)d_in[17];
    const float* rw    = (const float*)d_in[18];
    const float* rb    = (const float*)d_in[19];
    const float* aw    = (const float*)d_in[20];
    const float* ab    = (const float*)d_in[21];
    float* out = (float*)d_out;

    const long NBAT = (long)SS * DD;          // 1048576
    const long NBUF = (long)BB * SS * DD;     // 4194304
#define MB(x) ((long)(x) * 1048576L)

    char* P = (char*)d_ws;
    float* ada    = (float*)P;                       // 24576 f
    float* logits = (float*)(P + 98304);             // 16384 f
    float* comb   = logits + 16384;                  // 16384 f
    int*   tokidx = (int*)(comb + 16384);            // NSLOT
    int*   mbe    = tokidx + NSLOT;                  // NMB
    int*   mbm    = mbe + NMB;                       // NMB

    char* A0 = P + MB(1);
    // [0,12): wqT/wkT/wvT split -> woT [0,4) -> w1Tc [0,11.5)
    ushort* wqT_h = (ushort*)(A0 + MB(0));  ushort* wqT_l = (ushort*)(A0 + MB(2));
    ushort* wkT_h = (ushort*)(A0 + MB(4));  ushort* wkT_l = (ushort*)(A0 + MB(6));
    ushort* wvT_h = (ushort*)(A0 + MB(8));  ushort* wvT_l = (ushort*)(A0 + MB(10));
    ushort* woT_h = (ushort*)(A0 + MB(0));  ushort* woT_l = (ushort*)(A0 + MB(2));
    ushort* w1Tc  = (ushort*)(A0 + MB(0));           // [E][1408][1024] bf16
    // [12,28): h split -> sc -> ao split -> actb [8704][1408] (24.5 MiB)
    ushort* h_h  = (ushort*)(A0 + MB(12));  ushort* h_l  = (ushort*)(A0 + MB(20));
    float*  sc   = (float*) (A0 + MB(12));
    ushort* ao_h = (ushort*)(A0 + MB(12));  ushort* ao_l = (ushort*)(A0 + MB(20));
    ushort* actb = (ushort*)(A0 + MB(12));
    // [28,44): q32/k32 (sequenced) -> at split
    float*  qk32 = (float*) (A0 + MB(28));
    ushort* at_h = (ushort*)(A0 + MB(28));  ushort* at_l = (ushort*)(A0 + MB(36));
    // [44,60): v split
    ushort* v_h  = (ushort*)(A0 + MB(44));  ushort* v_l  = (ushort*)(A0 + MB(52));
    // [60,76): qT split -> x2 -> w3Tc [60,71.5)
    ushort* qT_h = (ushort*)(A0 + MB(60));  ushort* qT_l = (ushort*)(A0 + MB(68));
    float*  x2   = (float*) (A0 + MB(60));
    ushort* w3Tc = (ushort*)(A0 + MB(60));
    // [76,92): kT split -> h2bf [76,84); w2Tc [84,95.5)
    ushort* kT_h = (ushort*)(A0 + MB(76));  ushort* kT_l = (ushort*)(A0 + MB(84));
    ushort* h2bf = (ushort*)(A0 + MB(76));
    ushort* w2Tc = (ushort*)(A0 + MB(84));           // [E][1024][1408] bf16

    const dim3 blk(256);

    // 1. adaLN vector
    ada_kernel<<<dim3(SIXD/256, BB), blk, 0, stream>>>(adaln, aw, ab, ada);

    // 2. attention weight transposes (split)
    transp<true><<<dim3(16,16,1), blk, 0, stream>>>(wq, wqT_h, wqT_l, 1024, 1024, 0, 0);
    transp<true><<<dim3(16,16,1), blk, 0, stream>>>(wk, wkT_h, wkT_l, 1024, 1024, 0, 0);
    transp<true><<<dim3(16,16,1), blk, 0, stream>>>(wv, wvT_h, wvT_l, 1024, 1024, 0, 0);

    // 3. h = modulate(ln(x)) -> split bf16
    ln_kernel<1,true><<<4096, blk, 0, stream>>>(x, an_w, an_b, ada, 1024, 0,
                                                nullptr, h_h, h_l, 1e-5f);

    // 4. q: project, LN, transpose-split
    mgemm<0,true,false><<<dim3(16,32,1), blk, 0, stream>>>(
        h_h, h_l, wqT_h, wqT_l, qk32, nullptr, nullptr, nullptr, nullptr, nullptr, nullptr,
        1024, 1024, 1024, 1024, 0, 0, 0);
    ln_kernel<0,false><<<4096, blk, 0, stream>>>(qk32, qn_w, qn_b, ada, 0, 0, qk32, nullptr, nullptr, 1e-5f);
    transp<true><<<dim3(16,16,BB), blk, 0, stream>>>(qk32, qT_h, qT_l, 1024, 1024, NBAT, NBAT);

    // 5. k: project, LN, transpose-split
    mgemm<0,true,false><<<dim3(16,32,1), blk, 0, stream>>>(
        h_h, h_l, wkT_h, wkT_l, qk32, nullptr, nullptr, nullptr, nullptr, nullptr, nullptr,
        1024, 1024, 1024, 1024, 0, 0, 0);
    ln_kernel<0,false><<<4096, blk, 0, stream>>>(qk32, kn_w, kn_b, ada, 0, 0, qk32, nullptr, nullptr, 1e-5f);
    transp<true><<<dim3(16,16,BB), blk, 0, stream>>>(qk32, kT_h, kT_l, 1024, 1024, NBAT, NBAT);

    // 6. v: project -> split store
    mgemm<5,true,false><<<dim3(16,32,1), blk, 0, stream>>>(
        h_h, h_l, wvT_h, wvT_l, v_h, v_l, nullptr, nullptr, nullptr, nullptr, nullptr,
        1024, 1024, 1024, 1024, 0, 0, 0);

    // 7. wo transpose (into reclaimed wqT region)
    transp<true><<<dim3(16,16,1), blk, 0, stream>>>(wo, woT_h, woT_l, 1024, 1024, 0, 0);

    // 8. scores[b,d,e] = sum_s qT[b,d,s]*kT[b,e,s]
    mgemm<0,true,false><<<dim3(16,8,BB), blk, 0, stream>>>(
        qT_h, qT_l, kT_h, kT_l, sc, nullptr, nullptr, nullptr, nullptr, nullptr, nullptr,
        1024, 1024, 1024, 1024, NBAT, NBAT, NBAT);

    // 9. softmax -> attn split
    softmax_split<<<4096, blk, 0, stream>>>(sc, at_h, at_l);

    // 10. ao[b,s,d] = sum_e v[b,s,e]*attn[b,d,e] -> split store
    mgemm<5,true,false><<<dim3(16,8,BB), blk, 0, stream>>>(
        v_h, v_l, at_h, at_l, ao_h, ao_l, nullptr, nullptr, nullptr, nullptr, nullptr,
        1024, 1024, 1024, 1024, NBAT, NBAT, NBAT);

    // 11. x2 = x + gate_msa * (ao @ wo)
    mgemm<2,true,false><<<dim3(16,32,1), blk, 0, stream>>>(
        ao_h, ao_l, woT_h, woT_l, x2, nullptr, x, ada, nullptr, nullptr, nullptr,
        1024, 1024, 1024, 1024, 0, 0, 0);

    // 12. h2 = modulate(ln(x2)) -> bf16 (MoE input)
    ln_kernel<2,true><<<4096, blk, 0, stream>>>(x2, fn_w, fn_b, ada, 4096, 3072,
                                                nullptr, h2bf, nullptr, 1e-5f);

    // 13. router (exact fp32) + merged post/aux/compaction, zero out
    router_fused<<<4096, blk, 0, stream>>>(x2, fn_w, fn_b, ada, rw, rb, logits);
    router_all<<<1, dim3(1024), 0, stream>>>(logits, comb, out + NBUF, tokidx, mbe, mbm);
    zero_kernel<<<dim3(4096), blk, 0, stream>>>((float4*)out);

    // 14. MoE: top-2 sparse, HID chunked by 1408
    for (int c = 0; c < HID/HC; ++c) {
        transp<false><<<dim3(22,16,4), blk, 0, stream>>>(
            w1 + (long)c*HC, w1Tc, nullptr, HID, 1024, (long)DD*HID, (long)HC*1024);
        transp<false><<<dim3(22,16,4), blk, 0, stream>>>(
            w3 + (long)c*HC, w3Tc, nullptr, HID, 1024, (long)DD*HID, (long)HC*1024);
        transp<false><<<dim3(16,22,4), blk, 0, stream>>>(
            w2 + (long)c*HC*DD, w2Tc, nullptr, DD, HC, (long)HID*DD, (long)DD*HC);
        // act[slot] = bf16( sin(h2@w1c) * (h2@w3c) )  (gathered rows, dual-B)
        mgemm_h1h3<<<dim3(22, NMB), blk, 0, stream>>>(
            h2bf, w1Tc, w3Tc, actb, tokidx, mbe, mbm, (long)HC*1024);
        // out[token] += comb[token,e] * (act @ w2c)  (atomic scatter)
        mgemm<7,false,true><<<dim3(16, NMB), blk, 0, stream>>>(
            actb, nullptr, w2Tc, nullptr, out, nullptr, comb, nullptr, tokidx, mbe, mbm,
            HC, HC, HC, 1024, 0, (long)DD*HC, 0);
    }
#undef MB
}